// Round 1
// baseline (3080.303 us; speedup 1.0000x reference)
//
#include <hip/hip_runtime.h>
#include <math.h>

#define NN 50000
#define NE 600000
#define NP 200000

// ---------------- degree count ----------------
__global__ void k_deg(const int* __restrict__ dst, float* __restrict__ deg) {
    int e = blockIdx.x * 256 + threadIdx.x;
    if (e < NE) atomicAdd(deg + dst[e], 1.0f);
}

// ---------------- scatter x[src] -> agg1[dst], 128 dims, wave/edge ----------------
__global__ void k_scatter1(const float* __restrict__ x, const int* __restrict__ src,
                           const int* __restrict__ dst, float* __restrict__ agg) {
    int t = blockIdx.x * 256 + threadIdx.x;
    int e = t >> 6;
    if (e >= NE) return;
    int lane = t & 63;
    int s = src[e], d = dst[e];
    float2 v = *(const float2*)(x + (size_t)s * 128 + lane * 2);
    float* ap = agg + (size_t)d * 128 + lane * 2;
    atomicAdd(ap + 0, v.x);
    atomicAdd(ap + 1, v.y);
}

// ---------------- scatter h1[src] -> agg2[dst], 256 dims, wave/edge ----------------
__global__ void k_scatter2(const float* __restrict__ h, const int* __restrict__ src,
                           const int* __restrict__ dst, float* __restrict__ agg) {
    int t = blockIdx.x * 256 + threadIdx.x;
    int e = t >> 6;
    if (e >= NE) return;
    int lane = t & 63;
    int s = src[e], d = dst[e];
    float4 v = *(const float4*)(h + (size_t)s * 256 + lane * 4);
    float* ap = agg + (size_t)d * 256 + lane * 4;
    atomicAdd(ap + 0, v.x);
    atomicAdd(ap + 1, v.y);
    atomicAdd(ap + 2, v.z);
    atomicAdd(ap + 3, v.w);
}

// ---------------- layer 1: h1 = relu((agg1/deg)@W1l + b1l + x@W1r) ----------------
// block: 16 nodes x 256 cols, 256 threads, j = tid
__global__ __launch_bounds__(256) void k_l1(
    const float* __restrict__ x, const float* __restrict__ agg,
    const float* __restrict__ deg,
    const float* __restrict__ Wl, const float* __restrict__ bl,
    const float* __restrict__ Wr, float* __restrict__ h1) {
    __shared__ float xs[16 * 128];
    __shared__ float as[16 * 128];
    int n0 = blockIdx.x * 16;
    int tid = threadIdx.x;
    for (int idx = tid; idx < 16 * 128; idx += 256) {
        int n = idx >> 7;
        int k = idx & 127;
        float sc = 1.0f / fmaxf(deg[n0 + n], 1.0f);
        xs[idx] = x[(size_t)(n0 + n) * 128 + k];
        as[idx] = agg[(size_t)(n0 + n) * 128 + k] * sc;
    }
    __syncthreads();
    int j = tid;
    float acc[16];
#pragma unroll
    for (int i = 0; i < 16; i++) acc[i] = 0.f;
    for (int k = 0; k < 128; k++) {
        float wl = Wl[k * 256 + j];
        float wr = Wr[k * 256 + j];
#pragma unroll
        for (int i = 0; i < 16; i++)
            acc[i] = fmaf(as[i * 128 + k], wl, fmaf(xs[i * 128 + k], wr, acc[i]));
    }
    float b = bl[j];
#pragma unroll
    for (int i = 0; i < 16; i++) {
        float v = acc[i] + b;
        h1[(size_t)(n0 + i) * 256 + j] = v > 0.f ? v : 0.f;
    }
}

// ---------------- layer 2: h2 = (agg2/deg)@W2l + b2l + h1@W2r ----------------
// block: 16 nodes x 128 cols, 256 threads: j = tid&127, half = tid>>7 handles 8 nodes
__global__ __launch_bounds__(256) void k_l2(
    const float* __restrict__ h1, const float* __restrict__ agg,
    const float* __restrict__ deg,
    const float* __restrict__ Wl, const float* __restrict__ bl,
    const float* __restrict__ Wr, float* __restrict__ h2) {
    __shared__ float hs[16 * 256];
    __shared__ float as[16 * 256];
    int n0 = blockIdx.x * 16;
    int tid = threadIdx.x;
    for (int idx = tid; idx < 16 * 256; idx += 256) {
        int n = idx >> 8;
        int k = idx & 255;
        float sc = 1.0f / fmaxf(deg[n0 + n], 1.0f);
        hs[idx] = h1[(size_t)(n0 + n) * 256 + k];
        as[idx] = agg[(size_t)(n0 + n) * 256 + k] * sc;
    }
    __syncthreads();
    int j = tid & 127;
    int half = tid >> 7;
    float acc[8];
#pragma unroll
    for (int i = 0; i < 8; i++) acc[i] = 0.f;
    for (int k = 0; k < 256; k++) {
        float wl = Wl[k * 128 + j];
        float wr = Wr[k * 128 + j];
#pragma unroll
        for (int i = 0; i < 8; i++) {
            int n = half * 8 + i;
            acc[i] = fmaf(as[n * 256 + k], wl, fmaf(hs[n * 256 + k], wr, acc[i]));
        }
    }
    float b = bl[j];
#pragma unroll
    for (int i = 0; i < 8; i++)
        h2[(size_t)(n0 + half * 8 + i) * 128 + j] = acc[i] + b;
}

// ---------------- pair scorer: out = sigmoid([h2[a],h2[b]] @ Wlin + blin) ----------------
// one wave per pair
__global__ void k_pair(const float* __restrict__ h2, const int* __restrict__ mask,
                       const float* __restrict__ Wlin, const float* __restrict__ blin,
                       float* __restrict__ out) {
    int t = blockIdx.x * 256 + threadIdx.x;
    int p = t >> 6;
    if (p >= NP) return;
    int lane = t & 63;
    int a = mask[2 * p], b = mask[2 * p + 1];
    float v = h2[(size_t)a * 128 + lane]      * Wlin[lane]
            + h2[(size_t)a * 128 + 64 + lane] * Wlin[64 + lane]
            + h2[(size_t)b * 128 + lane]      * Wlin[128 + lane]
            + h2[(size_t)b * 128 + 64 + lane] * Wlin[192 + lane];
#pragma unroll
    for (int off = 32; off; off >>= 1) v += __shfl_xor(v, off, 64);
    if (lane == 0) out[p] = 1.0f / (1.0f + __expf(-(v + blin[0])));
}

extern "C" void kernel_launch(void* const* d_in, const int* in_sizes, int n_in,
                              void* d_out, int out_size, void* d_ws, size_t ws_size,
                              hipStream_t stream) {
    const float* x    = (const float*)d_in[0];   // [50000,128]
    const int*   ei   = (const int*)  d_in[1];   // [2,600000]
    const int*   mask = (const int*)  d_in[2];   // [200000,2]
    const float* W1l  = (const float*)d_in[3];   // [128,256]
    const float* b1l  = (const float*)d_in[4];   // [256]
    const float* W1r  = (const float*)d_in[5];   // [128,256]
    const float* W2l  = (const float*)d_in[6];   // [256,128]
    const float* b2l  = (const float*)d_in[7];   // [128]
    const float* W2r  = (const float*)d_in[8];   // [256,128]
    const float* Wlin = (const float*)d_in[9];   // [256,1]
    const float* blin = (const float*)d_in[10];  // [1]
    float* out = (float*)d_out;                  // [200000,1]

    const int* src = ei;
    const int* dst = ei + NE;

    // workspace layout (MB-aligned); h2 reuses agg1's region (dead after k_l1)
    char* ws = (char*)d_ws;
    float* deg  = (float*)(ws);                          // 50000 f   (0.2 MB)
    float* agg1 = (float*)(ws + (size_t)1  * (1 << 20)); // 50000*128 (25.6 MB)
    float* h1   = (float*)(ws + (size_t)27 * (1 << 20)); // 50000*256 (51.2 MB)
    float* agg2 = (float*)(ws + (size_t)79 * (1 << 20)); // 50000*256 (51.2 MB)
    float* h2   = agg1;                                  // reuse

    // zero accumulation buffers (ws is poisoned 0xAA before every launch)
    hipMemsetAsync(deg,  0, (size_t)NN * 4,        stream);
    hipMemsetAsync(agg1, 0, (size_t)NN * 128 * 4,  stream);
    hipMemsetAsync(agg2, 0, (size_t)NN * 256 * 4,  stream);

    k_deg<<<(NE + 255) / 256, 256, 0, stream>>>(dst, deg);
    k_scatter1<<<NE / 4, 256, 0, stream>>>(x, src, dst, agg1);
    k_l1<<<NN / 16, 256, 0, stream>>>(x, agg1, deg, W1l, b1l, W1r, h1);
    k_scatter2<<<NE / 4, 256, 0, stream>>>(h1, src, dst, agg2);
    k_l2<<<NN / 16, 256, 0, stream>>>(h1, agg2, deg, W2l, b2l, W2r, h2);
    k_pair<<<NP / 4, 256, 0, stream>>>(h2, mask, Wlin, blin, out);
}

// Round 2
// 785.144 us; speedup vs baseline: 3.9232x; 3.9232x over previous
//
#include <hip/hip_runtime.h>
#include <math.h>

#define NN 50000
#define NE 600000
#define NP 200000

// ---------------- int degree histogram ----------------
__global__ void k_deg(const int* __restrict__ dst, int* __restrict__ deg) {
    int e = blockIdx.x * 256 + threadIdx.x;
    if (e < NE) atomicAdd(deg + dst[e], 1);
}

// ---------------- exclusive scan of deg -> rowptr (single block, 1024 thr) ----------------
// Each thread owns a contiguous chunk of 49 elems (1024*49 = 50176 >= 50000):
// sequential local prefix, one Hillis-Steele LDS scan across thread totals, write back.
__global__ __launch_bounds__(1024) void k_scan(const int* __restrict__ deg,
                                               int* __restrict__ rowptr) {
    const int CHUNK = 49;
    int tid = threadIdx.x;
    int start = tid * CHUNK;
    int local[CHUNK];
    int sum = 0;
#pragma unroll
    for (int j = 0; j < CHUNK; j++) {
        int i = start + j;
        int v = (i < NN) ? deg[i] : 0;
        local[j] = sum;      // exclusive within chunk
        sum += v;
    }
    __shared__ int tmp[1024];
    tmp[tid] = sum;
    __syncthreads();
    int incl = sum;
    for (int off = 1; off < 1024; off <<= 1) {
        int t = (tid >= off) ? tmp[tid - off] : 0;
        __syncthreads();
        incl += t;
        tmp[tid] = incl;
        __syncthreads();
    }
    int excl = incl - sum;   // exclusive across chunks
#pragma unroll
    for (int j = 0; j < CHUNK; j++) {
        int i = start + j;
        if (i < NN) rowptr[i] = excl + local[j];
    }
    if (tid == 0) rowptr[NN] = NE;
}

// ---------------- edge placement: ssrc sorted by dst ----------------
__global__ void k_fill(const int* __restrict__ src, const int* __restrict__ dst,
                       int* __restrict__ cursor, int* __restrict__ ssrc) {
    int e = blockIdx.x * 256 + threadIdx.x;
    if (e >= NE) return;
    int d = dst[e];
    int pos = atomicAdd(cursor + d, 1);
    ssrc[pos] = src[e];
}

// ---------------- gather-mean over x (128 dims): wave per node ----------------
__global__ void k_agg1(const float* __restrict__ x, const int* __restrict__ rowptr,
                       const int* __restrict__ ssrc, float* __restrict__ agg) {
    int t = blockIdx.x * 256 + threadIdx.x;
    int n = t >> 6;
    if (n >= NN) return;
    int lane = t & 63;
    int r0 = rowptr[n], r1 = rowptr[n + 1];
    float ax = 0.f, ay = 0.f;
    for (int e = r0; e < r1; e++) {
        int s = ssrc[e];  // wave-uniform broadcast load
        float2 v = *(const float2*)(x + (size_t)s * 128 + lane * 2);
        ax += v.x; ay += v.y;
    }
    float sc = 1.0f / fmaxf((float)(r1 - r0), 1.0f);
    *(float2*)(agg + (size_t)n * 128 + lane * 2) = make_float2(ax * sc, ay * sc);
}

// ---------------- gather-mean over h1 (256 dims): wave per node ----------------
__global__ void k_agg2(const float* __restrict__ h, const int* __restrict__ rowptr,
                       const int* __restrict__ ssrc, float* __restrict__ agg) {
    int t = blockIdx.x * 256 + threadIdx.x;
    int n = t >> 6;
    if (n >= NN) return;
    int lane = t & 63;
    int r0 = rowptr[n], r1 = rowptr[n + 1];
    float ax = 0.f, ay = 0.f, az = 0.f, aw = 0.f;
    for (int e = r0; e < r1; e++) {
        int s = ssrc[e];
        float4 v = *(const float4*)(h + (size_t)s * 256 + lane * 4);
        ax += v.x; ay += v.y; az += v.z; aw += v.w;
    }
    float sc = 1.0f / fmaxf((float)(r1 - r0), 1.0f);
    *(float4*)(agg + (size_t)n * 256 + lane * 4) = make_float4(ax * sc, ay * sc, az * sc, aw * sc);
}

// ---------------- layer 1: h1 = relu(agg1m@W1l + b1l + x@W1r) ----------------
// block: 16 nodes x 256 cols, 256 threads, j = tid
__global__ __launch_bounds__(256) void k_l1(
    const float* __restrict__ x, const float* __restrict__ agg,
    const float* __restrict__ Wl, const float* __restrict__ bl,
    const float* __restrict__ Wr, float* __restrict__ h1) {
    __shared__ float xs[16 * 128];
    __shared__ float as[16 * 128];
    int n0 = blockIdx.x * 16;
    int tid = threadIdx.x;
    for (int idx = tid; idx < 16 * 128; idx += 256) {
        int n = idx >> 7;
        int k = idx & 127;
        xs[idx] = x[(size_t)(n0 + n) * 128 + k];
        as[idx] = agg[(size_t)(n0 + n) * 128 + k];
    }
    __syncthreads();
    int j = tid;
    float acc[16];
#pragma unroll
    for (int i = 0; i < 16; i++) acc[i] = 0.f;
    for (int k = 0; k < 128; k++) {
        float wl = Wl[k * 256 + j];
        float wr = Wr[k * 256 + j];
#pragma unroll
        for (int i = 0; i < 16; i++)
            acc[i] = fmaf(as[i * 128 + k], wl, fmaf(xs[i * 128 + k], wr, acc[i]));
    }
    float b = bl[j];
#pragma unroll
    for (int i = 0; i < 16; i++) {
        float v = acc[i] + b;
        h1[(size_t)(n0 + i) * 256 + j] = v > 0.f ? v : 0.f;
    }
}

// ---------------- layer 2: h2 = agg2m@W2l + b2l + h1@W2r ----------------
__global__ __launch_bounds__(256) void k_l2(
    const float* __restrict__ h1, const float* __restrict__ agg,
    const float* __restrict__ Wl, const float* __restrict__ bl,
    const float* __restrict__ Wr, float* __restrict__ h2) {
    __shared__ float hs[16 * 256];
    __shared__ float as[16 * 256];
    int n0 = blockIdx.x * 16;
    int tid = threadIdx.x;
    for (int idx = tid; idx < 16 * 256; idx += 256) {
        int n = idx >> 8;
        int k = idx & 255;
        hs[idx] = h1[(size_t)(n0 + n) * 256 + k];
        as[idx] = agg[(size_t)(n0 + n) * 256 + k];
    }
    __syncthreads();
    int j = tid & 127;
    int half = tid >> 7;
    float acc[8];
#pragma unroll
    for (int i = 0; i < 8; i++) acc[i] = 0.f;
    for (int k = 0; k < 256; k++) {
        float wl = Wl[k * 128 + j];
        float wr = Wr[k * 128 + j];
#pragma unroll
        for (int i = 0; i < 8; i++) {
            int n = half * 8 + i;
            acc[i] = fmaf(as[n * 256 + k], wl, fmaf(hs[n * 256 + k], wr, acc[i]));
        }
    }
    float b = bl[j];
#pragma unroll
    for (int i = 0; i < 8; i++)
        h2[(size_t)(n0 + half * 8 + i) * 128 + j] = acc[i] + b;
}

// ---------------- pair scorer: out = sigmoid([h2[a],h2[b]] @ Wlin + blin) ----------------
__global__ void k_pair(const float* __restrict__ h2, const int* __restrict__ mask,
                       const float* __restrict__ Wlin, const float* __restrict__ blin,
                       float* __restrict__ out) {
    int t = blockIdx.x * 256 + threadIdx.x;
    int p = t >> 6;
    if (p >= NP) return;
    int lane = t & 63;
    int a = mask[2 * p], b = mask[2 * p + 1];
    float v = h2[(size_t)a * 128 + lane]      * Wlin[lane]
            + h2[(size_t)a * 128 + 64 + lane] * Wlin[64 + lane]
            + h2[(size_t)b * 128 + lane]      * Wlin[128 + lane]
            + h2[(size_t)b * 128 + 64 + lane] * Wlin[192 + lane];
#pragma unroll
    for (int off = 32; off; off >>= 1) v += __shfl_xor(v, off, 64);
    if (lane == 0) out[p] = 1.0f / (1.0f + __expf(-(v + blin[0])));
}

extern "C" void kernel_launch(void* const* d_in, const int* in_sizes, int n_in,
                              void* d_out, int out_size, void* d_ws, size_t ws_size,
                              hipStream_t stream) {
    const float* x    = (const float*)d_in[0];   // [50000,128]
    const int*   ei   = (const int*)  d_in[1];   // [2,600000]
    const int*   mask = (const int*)  d_in[2];   // [200000,2]
    const float* W1l  = (const float*)d_in[3];   // [128,256]
    const float* b1l  = (const float*)d_in[4];   // [256]
    const float* W1r  = (const float*)d_in[5];   // [128,256]
    const float* W2l  = (const float*)d_in[6];   // [256,128]
    const float* b2l  = (const float*)d_in[7];   // [128]
    const float* W2r  = (const float*)d_in[8];   // [256,128]
    const float* Wlin = (const float*)d_in[9];   // [256,1]
    const float* blin = (const float*)d_in[10];  // [1]
    float* out = (float*)d_out;                  // [200000,1]

    const int* src = ei;
    const int* dst = ei + NE;

    // workspace layout
    char* ws = (char*)d_ws;
    int*   deg    = (int*)(ws);                          // 200 KB
    int*   rowptr = (int*)(ws + (size_t)1 * (1 << 20));  // (NN+1)*4
    int*   cursor = (int*)(ws + (size_t)2 * (1 << 20));  // NN*4
    int*   ssrc   = (int*)(ws + (size_t)3 * (1 << 20));  // NE*4 = 2.4 MB
    float* agg1m  = (float*)(ws + (size_t)6  * (1 << 20)); // 25.6 MB
    float* h1     = (float*)(ws + (size_t)32 * (1 << 20)); // 51.2 MB
    float* agg2m  = (float*)(ws + (size_t)84 * (1 << 20)); // 51.2 MB
    float* h2     = agg1m;  // agg1m dead after k_l1

    hipMemsetAsync(deg, 0, (size_t)NN * 4, stream);

    k_deg <<<(NE + 255) / 256, 256, 0, stream>>>(dst, deg);
    k_scan<<<1, 1024, 0, stream>>>(deg, rowptr);
    hipMemcpyAsync(cursor, rowptr, (size_t)NN * 4, hipMemcpyDeviceToDevice, stream);
    k_fill<<<(NE + 255) / 256, 256, 0, stream>>>(src, dst, cursor, ssrc);

    k_agg1<<<NN / 4, 256, 0, stream>>>(x, rowptr, ssrc, agg1m);
    k_l1  <<<NN / 16, 256, 0, stream>>>(x, agg1m, W1l, b1l, W1r, h1);
    k_agg2<<<NN / 4, 256, 0, stream>>>(h1, rowptr, ssrc, agg2m);
    k_l2  <<<NN / 16, 256, 0, stream>>>(h1, agg2m, W2l, b2l, W2r, h2);
    k_pair<<<NP / 4, 256, 0, stream>>>(h2, mask, Wlin, blin, out);
}

// Round 3
// 456.397 us; speedup vs baseline: 6.7492x; 1.7203x over previous
//
#include <hip/hip_runtime.h>
#include <math.h>

#define NN 50000
#define NE 600000
#define NP 200000

typedef unsigned int uint;
typedef unsigned short ushort;
typedef __attribute__((ext_vector_type(8))) short bf16x8;
typedef __attribute__((ext_vector_type(4))) float f32x4;

// ---- bf16 helpers (RNE) ----
__device__ __forceinline__ ushort f2bf(float f) {
    uint u = __float_as_uint(f);
    uint r = (u + 0x7FFFu + ((u >> 16) & 1u)) >> 16;
    return (ushort)r;
}
__device__ __forceinline__ float bf2f(uint lo16) {
    return __uint_as_float(lo16 << 16);
}

// ---------------- int degree histogram ----------------
__global__ void k_deg(const int* __restrict__ dst, int* __restrict__ deg) {
    int e = blockIdx.x * 256 + threadIdx.x;
    if (e < NE) atomicAdd(deg + dst[e], 1);
}

// ---------------- exclusive scan of deg -> rowptr (single block, 1024 thr) ----------------
__global__ __launch_bounds__(1024) void k_scan(const int* __restrict__ deg,
                                               int* __restrict__ rowptr) {
    const int CHUNK = 49;
    int tid = threadIdx.x;
    int start = tid * CHUNK;
    int local[CHUNK];
    int sum = 0;
#pragma unroll
    for (int j = 0; j < CHUNK; j++) {
        int i = start + j;
        int v = (i < NN) ? deg[i] : 0;
        local[j] = sum;
        sum += v;
    }
    __shared__ int tmp[1024];
    tmp[tid] = sum;
    __syncthreads();
    int incl = sum;
    for (int off = 1; off < 1024; off <<= 1) {
        int t = (tid >= off) ? tmp[tid - off] : 0;
        __syncthreads();
        incl += t;
        tmp[tid] = incl;
        __syncthreads();
    }
    int excl = incl - sum;
#pragma unroll
    for (int j = 0; j < CHUNK; j++) {
        int i = start + j;
        if (i < NN) rowptr[i] = excl + local[j];
    }
    if (tid == 0) rowptr[NN] = NE;
}

// ---------------- edge placement: ssrc sorted by dst ----------------
__global__ void k_fill(const int* __restrict__ src, const int* __restrict__ dst,
                       int* __restrict__ cursor, int* __restrict__ ssrc) {
    int e = blockIdx.x * 256 + threadIdx.x;
    if (e >= NE) return;
    int d = dst[e];
    int pos = atomicAdd(cursor + d, 1);
    ssrc[pos] = src[e];
}

// ---------------- convert x (fp32) -> bf16 into A1 right half ----------------
// A1 row = 256 bf16 = 128 uints; cols 128..255 (uints 64..127) = x
__global__ void k_prep(const float* __restrict__ x, uint* __restrict__ A1u) {
    int idx = blockIdx.x * 256 + threadIdx.x;  // NN*64 threads, 2 elems each
    if (idx >= NN * 64) return;
    int n = idx >> 6, c2 = idx & 63;
    float2 v = *(const float2*)(x + (size_t)n * 128 + c2 * 2);
    A1u[(size_t)n * 128 + 64 + c2] = (uint)f2bf(v.x) | ((uint)f2bf(v.y) << 16);
}

// ---------------- W prep: [Wt;Wb] stacked K-wise -> MFMA B-operand layout, bf16 ----
// Bp[((ct*(N/16)+nt)*64 + lane)*8 + j] = Wcat[ct*32 + (lane>>4)*8 + j][nt*16 + (lane&15)]
template <int K, int N>
__global__ void k_prepB(const float* __restrict__ Wt, const float* __restrict__ Wb,
                        ushort* __restrict__ Bp) {
    int idx = blockIdx.x * 256 + threadIdx.x;
    if (idx >= (K / 32) * (N / 16) * 64) return;
    int lane = idx & 63;
    int nt = (idx >> 6) % (N / 16);
    int ct = idx / (64 * (N / 16));
    int n = nt * 16 + (lane & 15);
    int kb = ct * 32 + (lane >> 4) * 8;
#pragma unroll
    for (int j = 0; j < 8; j++) {
        int k = kb + j;
        float w = (k < K / 2) ? Wt[(size_t)k * N + n] : Wb[(size_t)(k - K / 2) * N + n];
        Bp[(size_t)idx * 8 + j] = f2bf(w);
    }
}

// ---------------- gather-mean of x(bf16) -> A1 left half (bf16) ----------------
__global__ void k_agg1(uint* __restrict__ A1u, const int* __restrict__ rowptr,
                       const int* __restrict__ ssrc) {
    int t = blockIdx.x * 256 + threadIdx.x;
    int n = t >> 6;
    if (n >= NN) return;
    int lane = t & 63;
    int r0 = rowptr[n], r1 = rowptr[n + 1];
    float ax = 0.f, ay = 0.f;
    for (int e = r0; e < r1; e++) {
        int s = ssrc[e];  // wave-uniform
        uint v = A1u[(size_t)s * 128 + 64 + lane];
        ax += bf2f(v & 0xffffu);
        ay += bf2f(v >> 16);
    }
    float sc = 1.0f / fmaxf((float)(r1 - r0), 1.0f);
    A1u[(size_t)n * 128 + lane] = (uint)f2bf(ax * sc) | ((uint)f2bf(ay * sc) << 16);
}

// ---------------- gather-mean of h1(bf16, A2 right) -> A2 left (bf16) ----------------
// A2 row = 512 bf16 = 256 uints; h1 at uints 128..255, agg2 at uints 0..127
__global__ void k_agg2(uint* __restrict__ A2u, const int* __restrict__ rowptr,
                       const int* __restrict__ ssrc) {
    int t = blockIdx.x * 256 + threadIdx.x;
    int n = t >> 6;
    if (n >= NN) return;
    int lane = t & 63;
    int r0 = rowptr[n], r1 = rowptr[n + 1];
    float a0 = 0.f, a1 = 0.f, a2 = 0.f, a3 = 0.f;
    for (int e = r0; e < r1; e++) {
        int s = ssrc[e];
        uint2 v = *(const uint2*)(A2u + (size_t)s * 256 + 128 + lane * 2);
        a0 += bf2f(v.x & 0xffffu);
        a1 += bf2f(v.x >> 16);
        a2 += bf2f(v.y & 0xffffu);
        a3 += bf2f(v.y >> 16);
    }
    float sc = 1.0f / fmaxf((float)(r1 - r0), 1.0f);
    uint2 o;
    o.x = (uint)f2bf(a0 * sc) | ((uint)f2bf(a1 * sc) << 16);
    o.y = (uint)f2bf(a2 * sc) | ((uint)f2bf(a3 * sc) << 16);
    *(uint2*)(A2u + (size_t)n * 256 + lane * 2) = o;
}

// ---------------- MFMA GEMM: out[m, ooff+n] = bf16( A[m,:]@Wswz + bias[n] ) ------
// A: [M,K] bf16 row-major. Bp: pre-swizzled B operand. Tile 64 M/block, wave = 16 rows.
// Layouts (m89/m91-verified): A-frag A[m=lane&15][k=quad*8+j]; C/D col=lane&15,
// row=quad*4+reg.
template <int K, int N, bool RELU>
__global__ __launch_bounds__(256) void k_gemm(const ushort* __restrict__ A,
                                              const ushort* __restrict__ Bp,
                                              const float* __restrict__ bias,
                                              ushort* __restrict__ out, int ldo, int ooff) {
    const int NT = N / 16;
    int wave = threadIdx.x >> 6;
    int lane = threadIdx.x & 63;
    int quad = lane >> 4;
    int l15 = lane & 15;
    int m0 = blockIdx.x * 64 + wave * 16;
    int r = m0 + l15;
    if (r >= NN) r = NN - 1;  // tail: duplicate last row (stores guarded)
    f32x4 acc[NT];
#pragma unroll
    for (int i = 0; i < NT; i++) acc[i] = (f32x4){0.f, 0.f, 0.f, 0.f};
    const bf16x8* bp = (const bf16x8*)Bp;
#pragma unroll
    for (int ct = 0; ct < K / 32; ct++) {
        bf16x8 a = *(const bf16x8*)(A + (size_t)r * K + ct * 32 + quad * 8);
#pragma unroll
        for (int nt = 0; nt < NT; nt++) {
            bf16x8 b = bp[(ct * NT + nt) * 64 + lane];
            acc[nt] = __builtin_amdgcn_mfma_f32_16x16x32_bf16(a, b, acc[nt], 0, 0, 0);
        }
    }
    int mb = m0 + quad * 4;
#pragma unroll
    for (int nt = 0; nt < NT; nt++) {
        int col = nt * 16 + l15;
        float bv = bias[col];
#pragma unroll
        for (int reg = 0; reg < 4; reg++) {
            int m = mb + reg;
            if (m < NN) {
                float v = acc[nt][reg] + bv;
                if (RELU) v = v > 0.f ? v : 0.f;
                out[(size_t)m * ldo + ooff + col] = f2bf(v);
            }
        }
    }
}

// ---------------- pair scorer on bf16 h2 ----------------
__global__ void k_pair(const uint* __restrict__ h2u, const int* __restrict__ mask,
                       const float* __restrict__ Wlin, const float* __restrict__ blin,
                       float* __restrict__ out) {
    int t = blockIdx.x * 256 + threadIdx.x;
    int p = t >> 6;
    if (p >= NP) return;
    int lane = t & 63;
    int a = mask[2 * p], b = mask[2 * p + 1];
    uint va = h2u[(size_t)a * 64 + lane];  // h2 row = 64 uints (128 bf16)
    uint vb = h2u[(size_t)b * 64 + lane];
    float w0 = Wlin[2 * lane], w1 = Wlin[2 * lane + 1];
    float w2 = Wlin[128 + 2 * lane], w3 = Wlin[129 + 2 * lane];
    float v = bf2f(va & 0xffffu) * w0 + bf2f(va >> 16) * w1 +
              bf2f(vb & 0xffffu) * w2 + bf2f(vb >> 16) * w3;
#pragma unroll
    for (int off = 32; off; off >>= 1) v += __shfl_xor(v, off, 64);
    if (lane == 0) out[p] = 1.0f / (1.0f + __expf(-(v + blin[0])));
}

extern "C" void kernel_launch(void* const* d_in, const int* in_sizes, int n_in,
                              void* d_out, int out_size, void* d_ws, size_t ws_size,
                              hipStream_t stream) {
    const float* x    = (const float*)d_in[0];   // [50000,128]
    const int*   ei   = (const int*)  d_in[1];   // [2,600000]
    const int*   mask = (const int*)  d_in[2];   // [200000,2]
    const float* W1l  = (const float*)d_in[3];   // [128,256]
    const float* b1l  = (const float*)d_in[4];   // [256]
    const float* W1r  = (const float*)d_in[5];   // [128,256]
    const float* W2l  = (const float*)d_in[6];   // [256,128]
    const float* b2l  = (const float*)d_in[7];   // [128]
    const float* W2r  = (const float*)d_in[8];   // [256,128]
    const float* Wlin = (const float*)d_in[9];   // [256,1]
    const float* blin = (const float*)d_in[10];  // [1]
    float* out = (float*)d_out;                  // [200000,1]

    const int* src = ei;
    const int* dst = ei + NE;

    char* ws = (char*)d_ws;
    int*    deg    = (int*)(ws);                           // 200 KB
    int*    rowptr = (int*)(ws + (size_t)1 * (1 << 20));
    int*    cursor = (int*)(ws + (size_t)2 * (1 << 20));
    int*    ssrc   = (int*)(ws + (size_t)3 * (1 << 20));   // 2.4 MB
    ushort* Bp1    = (ushort*)(ws + (size_t)6 * (1 << 20)); // 128 KB
    ushort* Bp2    = (ushort*)(ws + (size_t)7 * (1 << 20)); // 128 KB
    uint*   A1u    = (uint*)(ws + (size_t)8 * (1 << 20));   // [50000,256] bf16 = 25.6 MB
    uint*   A2u    = (uint*)(ws + (size_t)34 * (1 << 20));  // [50000,512] bf16 = 51.2 MB
    uint*   h2u    = (uint*)(ws + (size_t)86 * (1 << 20));  // [50000,128] bf16 = 12.8 MB

    hipMemsetAsync(deg, 0, (size_t)NN * 4, stream);

    // CSR build
    k_deg <<<(NE + 255) / 256, 256, 0, stream>>>(dst, deg);
    k_scan<<<1, 1024, 0, stream>>>(deg, rowptr);
    hipMemcpyAsync(cursor, rowptr, (size_t)NN * 4, hipMemcpyDeviceToDevice, stream);
    k_fill<<<(NE + 255) / 256, 256, 0, stream>>>(src, dst, cursor, ssrc);

    // bf16 conversions
    k_prep<<<(NN * 64 + 255) / 256, 256, 0, stream>>>(x, A1u);
    k_prepB<256, 256><<<32, 256, 0, stream>>>(W1l, W1r, Bp1);
    k_prepB<512, 128><<<32, 256, 0, stream>>>(W2l, W2r, Bp2);

    // layer 1
    k_agg1<<<NN / 4, 256, 0, stream>>>(A1u, rowptr, ssrc);
    k_gemm<256, 256, true><<<(NN + 63) / 64, 256, 0, stream>>>(
        (const ushort*)A1u, Bp1, b1l, (ushort*)A2u, 512, 256);
    // layer 2
    k_agg2<<<NN / 4, 256, 0, stream>>>(A2u, rowptr, ssrc);
    k_gemm<512, 128, false><<<(NN + 63) / 64, 256, 0, stream>>>(
        (const ushort*)A2u, Bp2, b2l, (ushort*)h2u, 128, 0);
    // pair scorer
    k_pair<<<NP / 4, 256, 0, stream>>>(h2u, mask, Wlin, blin, out);
}

// Round 4
// 383.574 us; speedup vs baseline: 8.0305x; 1.1899x over previous
//
#include <hip/hip_runtime.h>
#include <math.h>

#define NN 50000
#define NE 600000
#define NP 200000

typedef unsigned int uint;
typedef unsigned short ushort;
typedef __attribute__((ext_vector_type(8))) short bf16x8;
typedef __attribute__((ext_vector_type(4))) float f32x4;

// ---- bf16 helpers (RNE) ----
__device__ __forceinline__ ushort f2bf(float f) {
    uint u = __float_as_uint(f);
    uint r = (u + 0x7FFFu + ((u >> 16) & 1u)) >> 16;
    return (ushort)r;
}
__device__ __forceinline__ float bf2f(uint lo16) {
    return __uint_as_float(lo16 << 16);
}

// ---- W swizzle into MFMA B-operand layout (bf16), device helper ----
// Bp[((ct*(N/16)+nt)*64 + lane)*8 + j] = Wcat[ct*32 + (lane>>4)*8 + j][nt*16 + (lane&15)]
template <int K, int N>
__device__ __forceinline__ void prepB_one(int idx, const float* __restrict__ Wt,
                                          const float* __restrict__ Wb,
                                          ushort* __restrict__ Bp) {
    int lane = idx & 63;
    int nt = (idx >> 6) % (N / 16);
    int ct = idx / (64 * (N / 16));
    int n = nt * 16 + (lane & 15);
    int kb = ct * 32 + (lane >> 4) * 8;
#pragma unroll
    for (int j = 0; j < 8; j++) {
        int k = kb + j;
        float w = (k < K / 2) ? Wt[(size_t)k * N + n] : Wb[(size_t)(k - K / 2) * N + n];
        Bp[(size_t)idx * 8 + j] = f2bf(w);
    }
}

// ---------------- fused prologue: deg histogram + x->bf16 + W swizzles ----------------
// thread ranges: [0, NN*64) x-convert | [.., +NE) deg | [.., +8192) Bp1 | [.., +8192) Bp2
#define T_PREP (NN * 64)
#define T_DEG  (T_PREP + NE)
#define T_B1   (T_DEG + 8192)
#define T_B2   (T_B1 + 8192)
__global__ void k_pre(const float* __restrict__ x, uint* __restrict__ A1u,
                      const int* __restrict__ dst, int* __restrict__ deg,
                      const float* __restrict__ W1l, const float* __restrict__ W1r,
                      ushort* __restrict__ Bp1,
                      const float* __restrict__ W2l, const float* __restrict__ W2r,
                      ushort* __restrict__ Bp2) {
    int t = blockIdx.x * 256 + threadIdx.x;
    if (t < T_PREP) {
        int n = t >> 6, c2 = t & 63;
        float2 v = *(const float2*)(x + (size_t)n * 128 + c2 * 2);
        A1u[(size_t)n * 128 + 64 + c2] = (uint)f2bf(v.x) | ((uint)f2bf(v.y) << 16);
    } else if (t < T_DEG) {
        atomicAdd(deg + dst[t - T_PREP], 1);
    } else if (t < T_B1) {
        prepB_one<256, 256>(t - T_DEG, W1l, W1r, Bp1);
    } else if (t < T_B2) {
        prepB_one<512, 128>(t - T_B1, W2l, W2r, Bp2);
    }
}

// ---------------- exclusive scan of deg -> rowptr + cursor (single block) ----------------
__global__ __launch_bounds__(1024) void k_scan(const int* __restrict__ deg,
                                               int* __restrict__ rowptr,
                                               int* __restrict__ cursor) {
    const int CHUNK = 49;
    int tid = threadIdx.x;
    int start = tid * CHUNK;
    int local[CHUNK];
    int sum = 0;
#pragma unroll
    for (int j = 0; j < CHUNK; j++) {
        int i = start + j;
        int v = (i < NN) ? deg[i] : 0;
        local[j] = sum;
        sum += v;
    }
    __shared__ int tmp[1024];
    tmp[tid] = sum;
    __syncthreads();
    int incl = sum;
    for (int off = 1; off < 1024; off <<= 1) {
        int t = (tid >= off) ? tmp[tid - off] : 0;
        __syncthreads();
        incl += t;
        tmp[tid] = incl;
        __syncthreads();
    }
    int excl = incl - sum;
#pragma unroll
    for (int j = 0; j < CHUNK; j++) {
        int i = start + j;
        if (i < NN) {
            int v = excl + local[j];
            rowptr[i] = v;
            cursor[i] = v;
        }
    }
    if (tid == 0) rowptr[NN] = NE;
}

// ---------------- edge placement: ssrc sorted by dst ----------------
__global__ void k_fill(const int* __restrict__ src, const int* __restrict__ dst,
                       int* __restrict__ cursor, int* __restrict__ ssrc) {
    int e = blockIdx.x * 256 + threadIdx.x;
    if (e >= NE) return;
    int d = dst[e];
    int pos = atomicAdd(cursor + d, 1);
    ssrc[pos] = src[e];
}

// ---------------- gather-mean of x(bf16) -> A1 left half; 4 edges in flight ----------------
__global__ void k_agg1(uint* __restrict__ A1u, const int* __restrict__ rowptr,
                       const int* __restrict__ ssrc) {
    int t = blockIdx.x * 256 + threadIdx.x;
    int n = t >> 6;
    if (n >= NN) return;
    int lane = t & 63;
    int r0 = rowptr[n], r1 = rowptr[n + 1];
    float ax0 = 0.f, ay0 = 0.f, ax1 = 0.f, ay1 = 0.f;
    float ax2 = 0.f, ay2 = 0.f, ax3 = 0.f, ay3 = 0.f;
    int e = r0;
    for (; e + 4 <= r1; e += 4) {
        int s0 = ssrc[e], s1 = ssrc[e + 1], s2 = ssrc[e + 2], s3 = ssrc[e + 3];
        uint v0 = A1u[(size_t)s0 * 128 + 64 + lane];
        uint v1 = A1u[(size_t)s1 * 128 + 64 + lane];
        uint v2 = A1u[(size_t)s2 * 128 + 64 + lane];
        uint v3 = A1u[(size_t)s3 * 128 + 64 + lane];
        ax0 += bf2f(v0 & 0xffffu); ay0 += bf2f(v0 >> 16);
        ax1 += bf2f(v1 & 0xffffu); ay1 += bf2f(v1 >> 16);
        ax2 += bf2f(v2 & 0xffffu); ay2 += bf2f(v2 >> 16);
        ax3 += bf2f(v3 & 0xffffu); ay3 += bf2f(v3 >> 16);
    }
    for (; e < r1; e++) {
        int s = ssrc[e];
        uint v = A1u[(size_t)s * 128 + 64 + lane];
        ax0 += bf2f(v & 0xffffu); ay0 += bf2f(v >> 16);
    }
    float ax = (ax0 + ax1) + (ax2 + ax3);
    float ay = (ay0 + ay1) + (ay2 + ay3);
    float sc = 1.0f / fmaxf((float)(r1 - r0), 1.0f);
    A1u[(size_t)n * 128 + lane] = (uint)f2bf(ax * sc) | ((uint)f2bf(ay * sc) << 16);
}

// ---------------- gather-mean of h1(bf16, A2 right) -> A2 left; 4 edges in flight --------
__global__ void k_agg2(uint* __restrict__ A2u, const int* __restrict__ rowptr,
                       const int* __restrict__ ssrc) {
    int t = blockIdx.x * 256 + threadIdx.x;
    int n = t >> 6;
    if (n >= NN) return;
    int lane = t & 63;
    int r0 = rowptr[n], r1 = rowptr[n + 1];
    float a0[4] = {0.f, 0.f, 0.f, 0.f};
    float a1[4] = {0.f, 0.f, 0.f, 0.f};
    float a2[4] = {0.f, 0.f, 0.f, 0.f};
    float a3[4] = {0.f, 0.f, 0.f, 0.f};
    int e = r0;
    for (; e + 4 <= r1; e += 4) {
        int s0 = ssrc[e], s1 = ssrc[e + 1], s2 = ssrc[e + 2], s3 = ssrc[e + 3];
        uint2 v0 = *(const uint2*)(A2u + (size_t)s0 * 256 + 128 + lane * 2);
        uint2 v1 = *(const uint2*)(A2u + (size_t)s1 * 256 + 128 + lane * 2);
        uint2 v2 = *(const uint2*)(A2u + (size_t)s2 * 256 + 128 + lane * 2);
        uint2 v3 = *(const uint2*)(A2u + (size_t)s3 * 256 + 128 + lane * 2);
        a0[0] += bf2f(v0.x & 0xffffu); a0[1] += bf2f(v0.x >> 16);
        a0[2] += bf2f(v0.y & 0xffffu); a0[3] += bf2f(v0.y >> 16);
        a1[0] += bf2f(v1.x & 0xffffu); a1[1] += bf2f(v1.x >> 16);
        a1[2] += bf2f(v1.y & 0xffffu); a1[3] += bf2f(v1.y >> 16);
        a2[0] += bf2f(v2.x & 0xffffu); a2[1] += bf2f(v2.x >> 16);
        a2[2] += bf2f(v2.y & 0xffffu); a2[3] += bf2f(v2.y >> 16);
        a3[0] += bf2f(v3.x & 0xffffu); a3[1] += bf2f(v3.x >> 16);
        a3[2] += bf2f(v3.y & 0xffffu); a3[3] += bf2f(v3.y >> 16);
    }
    for (; e < r1; e++) {
        int s = ssrc[e];
        uint2 v = *(const uint2*)(A2u + (size_t)s * 256 + 128 + lane * 2);
        a0[0] += bf2f(v.x & 0xffffu); a0[1] += bf2f(v.x >> 16);
        a0[2] += bf2f(v.y & 0xffffu); a0[3] += bf2f(v.y >> 16);
    }
    float sc = 1.0f / fmaxf((float)(r1 - r0), 1.0f);
    float r00 = ((a0[0] + a1[0]) + (a2[0] + a3[0])) * sc;
    float r01 = ((a0[1] + a1[1]) + (a2[1] + a3[1])) * sc;
    float r10 = ((a0[2] + a1[2]) + (a2[2] + a3[2])) * sc;
    float r11 = ((a0[3] + a1[3]) + (a2[3] + a3[3])) * sc;
    uint2 o;
    o.x = (uint)f2bf(r00) | ((uint)f2bf(r01) << 16);
    o.y = (uint)f2bf(r10) | ((uint)f2bf(r11) << 16);
    *(uint2*)(A2u + (size_t)n * 256 + lane * 2) = o;
}

// ---------------- layer-1 GEMM: A2 right half = relu(A1@[W1l;W1r] + b1l), bf16 --------
// A: [NN,256] bf16. Tile 64 rows/block, wave = 16 rows. Layouts (m89/m91-verified):
// A-frag A[m=lane&15][k=quad*8+j]; C/D col=lane&15, row=quad*4+reg.
__global__ __launch_bounds__(256) void k_gemm1(const ushort* __restrict__ A,
                                               const ushort* __restrict__ Bp,
                                               const float* __restrict__ bias,
                                               ushort* __restrict__ out) {
    const int K = 256, NT = 16;
    int wave = threadIdx.x >> 6;
    int lane = threadIdx.x & 63;
    int quad = lane >> 4;
    int l15 = lane & 15;
    int m0 = blockIdx.x * 64 + wave * 16;
    int r = m0 + l15;
    if (r >= NN) r = NN - 1;
    f32x4 acc[NT];
#pragma unroll
    for (int i = 0; i < NT; i++) acc[i] = (f32x4){0.f, 0.f, 0.f, 0.f};
    const bf16x8* bp = (const bf16x8*)Bp;
#pragma unroll
    for (int ct = 0; ct < K / 32; ct++) {
        bf16x8 a = *(const bf16x8*)(A + (size_t)r * K + ct * 32 + quad * 8);
#pragma unroll
        for (int nt = 0; nt < NT; nt++) {
            bf16x8 b = bp[(ct * NT + nt) * 64 + lane];
            acc[nt] = __builtin_amdgcn_mfma_f32_16x16x32_bf16(a, b, acc[nt], 0, 0, 0);
        }
    }
    int mb = m0 + quad * 4;
#pragma unroll
    for (int nt = 0; nt < NT; nt++) {
        int col = nt * 16 + l15;
        float bv = bias[col];
#pragma unroll
        for (int reg = 0; reg < 4; reg++) {
            int m = mb + reg;
            if (m < NN) {
                float v = acc[nt][reg] + bv;
                out[(size_t)m * 512 + 256 + col] = f2bf(v > 0.f ? v : 0.f);
            }
        }
    }
}

// ---------------- layer-2 GEMM + fused Wlin dot: sa/sb per node, h2 never stored -------
// sa[m] = (A2[m]@[W2l;W2r] + b2l) . Wlin[0:128];  sb[m] = same . Wlin[128:256]
__global__ __launch_bounds__(256) void k_gemm2(const ushort* __restrict__ A,
                                               const ushort* __restrict__ Bp,
                                               const float* __restrict__ bias,
                                               const float* __restrict__ Wlin,
                                               float* __restrict__ sa,
                                               float* __restrict__ sb) {
    const int K = 512, NT = 8;
    int wave = threadIdx.x >> 6;
    int lane = threadIdx.x & 63;
    int quad = lane >> 4;
    int l15 = lane & 15;
    int m0 = blockIdx.x * 64 + wave * 16;
    int r = m0 + l15;
    if (r >= NN) r = NN - 1;
    f32x4 acc[NT];
#pragma unroll
    for (int i = 0; i < NT; i++) acc[i] = (f32x4){0.f, 0.f, 0.f, 0.f};
    const bf16x8* bp = (const bf16x8*)Bp;
#pragma unroll
    for (int ct = 0; ct < K / 32; ct++) {
        bf16x8 a = *(const bf16x8*)(A + (size_t)r * K + ct * 32 + quad * 8);
#pragma unroll
        for (int nt = 0; nt < NT; nt++) {
            bf16x8 b = bp[(ct * NT + nt) * 64 + lane];
            acc[nt] = __builtin_amdgcn_mfma_f32_16x16x32_bf16(a, b, acc[nt], 0, 0, 0);
        }
    }
    // epilogue: per-lane partial dots over this lane's 8 cols, for 4 rows (quad,reg)
    float pa[4] = {0.f, 0.f, 0.f, 0.f};
    float pb[4] = {0.f, 0.f, 0.f, 0.f};
#pragma unroll
    for (int nt = 0; nt < NT; nt++) {
        int col = nt * 16 + l15;
        float bv = bias[col];
        float w0 = Wlin[col];
        float w1 = Wlin[128 + col];
#pragma unroll
        for (int reg = 0; reg < 4; reg++) {
            float v = acc[nt][reg] + bv;
            pa[reg] += v * w0;
            pb[reg] += v * w1;
        }
    }
    // reduce across the 16 col-lanes of each quad (xor of low 4 lane bits stays in quad)
#pragma unroll
    for (int off = 1; off < 16; off <<= 1) {
#pragma unroll
        for (int reg = 0; reg < 4; reg++) {
            pa[reg] += __shfl_xor(pa[reg], off, 64);
            pb[reg] += __shfl_xor(pb[reg], off, 64);
        }
    }
    if (l15 == 0) {
        int mb = m0 + quad * 4;
#pragma unroll
        for (int reg = 0; reg < 4; reg++) {
            int m = mb + reg;
            if (m < NN) { sa[m] = pa[reg]; sb[m] = pb[reg]; }
        }
    }
}

// ---------------- pair scorer: out[p] = sigmoid(sa[a] + sb[b] + blin) ----------------
__global__ void k_pairs(const float* __restrict__ sa, const float* __restrict__ sb,
                        const int* __restrict__ mask, const float* __restrict__ blin,
                        float* __restrict__ out) {
    int p = blockIdx.x * 256 + threadIdx.x;
    if (p >= NP) return;
    int2 m = ((const int2*)mask)[p];
    float v = sa[m.x] + sb[m.y] + blin[0];
    out[p] = 1.0f / (1.0f + __expf(-v));
}

extern "C" void kernel_launch(void* const* d_in, const int* in_sizes, int n_in,
                              void* d_out, int out_size, void* d_ws, size_t ws_size,
                              hipStream_t stream) {
    const float* x    = (const float*)d_in[0];   // [50000,128]
    const int*   ei   = (const int*)  d_in[1];   // [2,600000]
    const int*   mask = (const int*)  d_in[2];   // [200000,2]
    const float* W1l  = (const float*)d_in[3];   // [128,256]
    const float* b1l  = (const float*)d_in[4];   // [256]
    const float* W1r  = (const float*)d_in[5];   // [128,256]
    const float* W2l  = (const float*)d_in[6];   // [256,128]
    const float* b2l  = (const float*)d_in[7];   // [128]
    const float* W2r  = (const float*)d_in[8];   // [256,128]
    const float* Wlin = (const float*)d_in[9];   // [256,1]
    const float* blin = (const float*)d_in[10];  // [1]
    float* out = (float*)d_out;                  // [200000,1]

    const int* src = ei;
    const int* dst = ei + NE;

    char* ws = (char*)d_ws;
    int*    deg    = (int*)(ws);                            // 200 KB
    int*    rowptr = (int*)(ws + (size_t)1 * (1 << 20));
    int*    cursor = (int*)(ws + (size_t)2 * (1 << 20));
    int*    ssrc   = (int*)(ws + (size_t)3 * (1 << 20));    // 2.4 MB
    ushort* Bp1    = (ushort*)(ws + (size_t)6 * (1 << 20)); // 128 KB
    ushort* Bp2    = (ushort*)(ws + (size_t)7 * (1 << 20)); // 128 KB
    float*  sa     = (float*)(ws + (size_t)8 * (1 << 20));  // 200 KB
    float*  sb     = (float*)(ws + (size_t)9 * (1 << 20));  // 200 KB
    uint*   A1u    = (uint*)(ws + (size_t)10 * (1 << 20));  // [50000,256] bf16 = 25.6 MB
    uint*   A2u    = (uint*)(ws + (size_t)36 * (1 << 20));  // [50000,512] bf16 = 51.2 MB

    hipMemsetAsync(deg, 0, (size_t)NN * 4, stream);

    k_pre <<<(T_B2 + 255) / 256, 256, 0, stream>>>(x, A1u, dst, deg,
                                                   W1l, W1r, Bp1, W2l, W2r, Bp2);
    k_scan<<<1, 1024, 0, stream>>>(deg, rowptr, cursor);
    k_fill<<<(NE + 255) / 256, 256, 0, stream>>>(src, dst, cursor, ssrc);

    k_agg1 <<<NN / 4, 256, 0, stream>>>(A1u, rowptr, ssrc);
    k_gemm1<<<(NN + 63) / 64, 256, 0, stream>>>((const ushort*)A1u, Bp1, b1l,
                                                (ushort*)A2u);
    k_agg2 <<<NN / 4, 256, 0, stream>>>(A2u, rowptr, ssrc);
    k_gemm2<<<(NN + 63) / 64, 256, 0, stream>>>((const ushort*)A2u, Bp2, b2l, Wlin,
                                                sa, sb);
    k_pairs<<<(NP + 255) / 256, 256, 0, stream>>>(sa, sb, mask, blin, out);
}

// Round 5
// 312.589 us; speedup vs baseline: 9.8542x; 1.2271x over previous
//
#include <hip/hip_runtime.h>
#include <math.h>

#define NN 50000
#define NE 600000
#define NP 200000
#define NB_SCAN 49  // ceil(NN / 1024)

typedef unsigned int uint;
typedef unsigned short ushort;
typedef __attribute__((ext_vector_type(8))) short bf16x8;
typedef __attribute__((ext_vector_type(4))) float f32x4;

// ---- bf16 helpers (RNE) ----
__device__ __forceinline__ ushort f2bf(float f) {
    uint u = __float_as_uint(f);
    uint r = (u + 0x7FFFu + ((u >> 16) & 1u)) >> 16;
    return (ushort)r;
}
__device__ __forceinline__ float bf2f(uint lo16) {
    return __uint_as_float(lo16 << 16);
}

__device__ __forceinline__ int wave_iscan(int v, int lane) {
#pragma unroll
    for (int off = 1; off < 64; off <<= 1) {
        int t = __shfl_up(v, off, 64);
        if (lane >= off) v += t;
    }
    return v;
}

// ---- W swizzle into MFMA B-operand layout (bf16), device helper ----
// Bp[((ct*(N/16)+nt)*64 + lane)*8 + j] = Wcat[ct*32 + (lane>>4)*8 + j][nt*16 + (lane&15)]
template <int K, int N>
__device__ __forceinline__ void prepB_one(int idx, const float* __restrict__ Wt,
                                          const float* __restrict__ Wb,
                                          ushort* __restrict__ Bp) {
    int lane = idx & 63;
    int nt = (idx >> 6) % (N / 16);
    int ct = idx / (64 * (N / 16));
    int n = nt * 16 + (lane & 15);
    int kb = ct * 32 + (lane >> 4) * 8;
#pragma unroll
    for (int j = 0; j < 8; j++) {
        int k = kb + j;
        float w = (k < K / 2) ? Wt[(size_t)k * N + n] : Wb[(size_t)(k - K / 2) * N + n];
        Bp[(size_t)idx * 8 + j] = f2bf(w);
    }
}

// ---------------- fused prologue: deg histogram + x->bf16 + W swizzles ----------------
#define T_PREP (NN * 64)
#define T_DEG  (T_PREP + NE)
#define T_B1   (T_DEG + 8192)
#define T_B2   (T_B1 + 8192)
__global__ void k_pre(const float* __restrict__ x, uint* __restrict__ A1u,
                      const int* __restrict__ dst, int* __restrict__ deg,
                      const float* __restrict__ W1l, const float* __restrict__ W1r,
                      ushort* __restrict__ Bp1,
                      const float* __restrict__ W2l, const float* __restrict__ W2r,
                      ushort* __restrict__ Bp2) {
    int t = blockIdx.x * 256 + threadIdx.x;
    if (t < T_PREP) {
        int n = t >> 6, c2 = t & 63;
        float2 v = *(const float2*)(x + (size_t)n * 128 + c2 * 2);
        A1u[(size_t)n * 128 + 64 + c2] = (uint)f2bf(v.x) | ((uint)f2bf(v.y) << 16);
    } else if (t < T_DEG) {
        atomicAdd(deg + dst[t - T_PREP], 1);
    } else if (t < T_B1) {
        prepB_one<256, 256>(t - T_DEG, W1l, W1r, Bp1);
    } else if (t < T_B2) {
        prepB_one<512, 128>(t - T_B1, W2l, W2r, Bp2);
    }
}

// ---------------- 3-phase grid-wide exclusive scan of deg ----------------
// phase 1: per-block exclusive values + block sums
__global__ __launch_bounds__(1024) void k_scan1(const int* __restrict__ deg,
                                                int* __restrict__ excl,
                                                int* __restrict__ bsum) {
    int tid = threadIdx.x;
    int i = blockIdx.x * 1024 + tid;
    int lane = tid & 63, wid = tid >> 6;
    int v = (i < NN) ? deg[i] : 0;
    int incl = wave_iscan(v, lane);
    __shared__ int wt[16];
    if (lane == 63) wt[wid] = incl;
    __syncthreads();
    if (tid < 16) {
        int w = wt[tid];
#pragma unroll
        for (int off = 1; off < 16; off <<= 1) {
            int t = __shfl_up(w, off, 64);
            if (tid >= off) w += t;
        }
        wt[tid] = w;  // inclusive across waves
    }
    __syncthreads();
    int base = (wid > 0) ? wt[wid - 1] : 0;
    if (i < NN) excl[i] = incl - v + base;
    if (tid == 0) bsum[blockIdx.x] = wt[15];
}

// phase 2: one wave scans the 49 block sums -> exclusive, in place
__global__ void k_scan2(int* __restrict__ bsum) {
    int lane = threadIdx.x;
    int v = (lane < NB_SCAN) ? bsum[lane] : 0;
    int incl = wave_iscan(v, lane);
    if (lane < NB_SCAN) bsum[lane] = incl - v;
}

// phase 3: add block offsets, write rowptr + cursor
__global__ __launch_bounds__(1024) void k_scan3(const int* __restrict__ excl,
                                                const int* __restrict__ bsum,
                                                int* __restrict__ rowptr,
                                                int* __restrict__ cursor) {
    int i = blockIdx.x * 1024 + threadIdx.x;
    if (i < NN) {
        int v = excl[i] + bsum[blockIdx.x];
        rowptr[i] = v;
        cursor[i] = v;
    }
    if (i == 0) rowptr[NN] = NE;
}

// ---------------- edge placement: ssrc sorted by dst ----------------
__global__ void k_fill(const int* __restrict__ src, const int* __restrict__ dst,
                       int* __restrict__ cursor, int* __restrict__ ssrc) {
    int e = blockIdx.x * 256 + threadIdx.x;
    if (e >= NE) return;
    int d = dst[e];
    int pos = atomicAdd(cursor + d, 1);
    ssrc[pos] = src[e];
}

// ---------------- gather-mean of x(bf16) -> A1 left half; 4 edges in flight ----------------
__global__ void k_agg1(uint* __restrict__ A1u, const int* __restrict__ rowptr,
                       const int* __restrict__ ssrc) {
    int t = blockIdx.x * 256 + threadIdx.x;
    int n = t >> 6;
    if (n >= NN) return;
    int lane = t & 63;
    int r0 = rowptr[n], r1 = rowptr[n + 1];
    float ax0 = 0.f, ay0 = 0.f, ax1 = 0.f, ay1 = 0.f;
    float ax2 = 0.f, ay2 = 0.f, ax3 = 0.f, ay3 = 0.f;
    int e = r0;
    for (; e + 4 <= r1; e += 4) {
        int s0 = ssrc[e], s1 = ssrc[e + 1], s2 = ssrc[e + 2], s3 = ssrc[e + 3];
        uint v0 = A1u[(size_t)s0 * 128 + 64 + lane];
        uint v1 = A1u[(size_t)s1 * 128 + 64 + lane];
        uint v2 = A1u[(size_t)s2 * 128 + 64 + lane];
        uint v3 = A1u[(size_t)s3 * 128 + 64 + lane];
        ax0 += bf2f(v0 & 0xffffu); ay0 += bf2f(v0 >> 16);
        ax1 += bf2f(v1 & 0xffffu); ay1 += bf2f(v1 >> 16);
        ax2 += bf2f(v2 & 0xffffu); ay2 += bf2f(v2 >> 16);
        ax3 += bf2f(v3 & 0xffffu); ay3 += bf2f(v3 >> 16);
    }
    for (; e < r1; e++) {
        int s = ssrc[e];
        uint v = A1u[(size_t)s * 128 + 64 + lane];
        ax0 += bf2f(v & 0xffffu); ay0 += bf2f(v >> 16);
    }
    float ax = (ax0 + ax1) + (ax2 + ax3);
    float ay = (ay0 + ay1) + (ay2 + ay3);
    float sc = 1.0f / fmaxf((float)(r1 - r0), 1.0f);
    A1u[(size_t)n * 128 + lane] = (uint)f2bf(ax * sc) | ((uint)f2bf(ay * sc) << 16);
}

// ---------------- gather-mean of h1(bf16, A2 right) -> A2 left; 4 edges in flight --------
__global__ void k_agg2(uint* __restrict__ A2u, const int* __restrict__ rowptr,
                       const int* __restrict__ ssrc) {
    int t = blockIdx.x * 256 + threadIdx.x;
    int n = t >> 6;
    if (n >= NN) return;
    int lane = t & 63;
    int r0 = rowptr[n], r1 = rowptr[n + 1];
    float a0[4] = {0.f, 0.f, 0.f, 0.f};
    float a1[4] = {0.f, 0.f, 0.f, 0.f};
    float a2[4] = {0.f, 0.f, 0.f, 0.f};
    float a3[4] = {0.f, 0.f, 0.f, 0.f};
    int e = r0;
    for (; e + 4 <= r1; e += 4) {
        int s0 = ssrc[e], s1 = ssrc[e + 1], s2 = ssrc[e + 2], s3 = ssrc[e + 3];
        uint2 v0 = *(const uint2*)(A2u + (size_t)s0 * 256 + 128 + lane * 2);
        uint2 v1 = *(const uint2*)(A2u + (size_t)s1 * 256 + 128 + lane * 2);
        uint2 v2 = *(const uint2*)(A2u + (size_t)s2 * 256 + 128 + lane * 2);
        uint2 v3 = *(const uint2*)(A2u + (size_t)s3 * 256 + 128 + lane * 2);
        a0[0] += bf2f(v0.x & 0xffffu); a0[1] += bf2f(v0.x >> 16);
        a0[2] += bf2f(v0.y & 0xffffu); a0[3] += bf2f(v0.y >> 16);
        a1[0] += bf2f(v1.x & 0xffffu); a1[1] += bf2f(v1.x >> 16);
        a1[2] += bf2f(v1.y & 0xffffu); a1[3] += bf2f(v1.y >> 16);
        a2[0] += bf2f(v2.x & 0xffffu); a2[1] += bf2f(v2.x >> 16);
        a2[2] += bf2f(v2.y & 0xffffu); a2[3] += bf2f(v2.y >> 16);
        a3[0] += bf2f(v3.x & 0xffffu); a3[1] += bf2f(v3.x >> 16);
        a3[2] += bf2f(v3.y & 0xffffu); a3[3] += bf2f(v3.y >> 16);
    }
    for (; e < r1; e++) {
        int s = ssrc[e];
        uint2 v = *(const uint2*)(A2u + (size_t)s * 256 + 128 + lane * 2);
        a0[0] += bf2f(v.x & 0xffffu); a0[1] += bf2f(v.x >> 16);
        a0[2] += bf2f(v.y & 0xffffu); a0[3] += bf2f(v.y >> 16);
    }
    float sc = 1.0f / fmaxf((float)(r1 - r0), 1.0f);
    float r00 = ((a0[0] + a1[0]) + (a2[0] + a3[0])) * sc;
    float r01 = ((a0[1] + a1[1]) + (a2[1] + a3[1])) * sc;
    float r10 = ((a0[2] + a1[2]) + (a2[2] + a3[2])) * sc;
    float r11 = ((a0[3] + a1[3]) + (a2[3] + a3[3])) * sc;
    uint2 o;
    o.x = (uint)f2bf(r00) | ((uint)f2bf(r01) << 16);
    o.y = (uint)f2bf(r10) | ((uint)f2bf(r11) << 16);
    *(uint2*)(A2u + (size_t)n * 256 + lane * 2) = o;
}

// ---------------- layer-1 GEMM: A2 right half = relu(A1@[W1l;W1r] + b1l), bf16 --------
// Layouts (m89/m91-verified): A-frag A[m=lane&15][k=quad*8+j]; C/D col=lane&15, row=quad*4+reg.
__global__ __launch_bounds__(256) void k_gemm1(const ushort* __restrict__ A,
                                               const ushort* __restrict__ Bp,
                                               const float* __restrict__ bias,
                                               ushort* __restrict__ out) {
    const int K = 256, NT = 16;
    int wave = threadIdx.x >> 6;
    int lane = threadIdx.x & 63;
    int quad = lane >> 4;
    int l15 = lane & 15;
    int m0 = blockIdx.x * 64 + wave * 16;
    int r = m0 + l15;
    if (r >= NN) r = NN - 1;
    f32x4 acc[NT];
#pragma unroll
    for (int i = 0; i < NT; i++) acc[i] = (f32x4){0.f, 0.f, 0.f, 0.f};
    const bf16x8* bp = (const bf16x8*)Bp;
#pragma unroll
    for (int ct = 0; ct < K / 32; ct++) {
        bf16x8 a = *(const bf16x8*)(A + (size_t)r * K + ct * 32 + quad * 8);
#pragma unroll
        for (int nt = 0; nt < NT; nt++) {
            bf16x8 b = bp[(ct * NT + nt) * 64 + lane];
            acc[nt] = __builtin_amdgcn_mfma_f32_16x16x32_bf16(a, b, acc[nt], 0, 0, 0);
        }
    }
    int mb = m0 + quad * 4;
#pragma unroll
    for (int nt = 0; nt < NT; nt++) {
        int col = nt * 16 + l15;
        float bv = bias[col];
#pragma unroll
        for (int reg = 0; reg < 4; reg++) {
            int m = mb + reg;
            if (m < NN) {
                float v = acc[nt][reg] + bv;
                out[(size_t)m * 512 + 256 + col] = f2bf(v > 0.f ? v : 0.f);
            }
        }
    }
}

// ---------------- layer-2 GEMM + fused Wlin dot: sa/sb per node, h2 never stored -------
__global__ __launch_bounds__(256) void k_gemm2(const ushort* __restrict__ A,
                                               const ushort* __restrict__ Bp,
                                               const float* __restrict__ bias,
                                               const float* __restrict__ Wlin,
                                               float* __restrict__ sa,
                                               float* __restrict__ sb) {
    const int K = 512, NT = 8;
    int wave = threadIdx.x >> 6;
    int lane = threadIdx.x & 63;
    int quad = lane >> 4;
    int l15 = lane & 15;
    int m0 = blockIdx.x * 64 + wave * 16;
    int r = m0 + l15;
    if (r >= NN) r = NN - 1;
    f32x4 acc[NT];
#pragma unroll
    for (int i = 0; i < NT; i++) acc[i] = (f32x4){0.f, 0.f, 0.f, 0.f};
    const bf16x8* bp = (const bf16x8*)Bp;
#pragma unroll
    for (int ct = 0; ct < K / 32; ct++) {
        bf16x8 a = *(const bf16x8*)(A + (size_t)r * K + ct * 32 + quad * 8);
#pragma unroll
        for (int nt = 0; nt < NT; nt++) {
            bf16x8 b = bp[(ct * NT + nt) * 64 + lane];
            acc[nt] = __builtin_amdgcn_mfma_f32_16x16x32_bf16(a, b, acc[nt], 0, 0, 0);
        }
    }
    float pa[4] = {0.f, 0.f, 0.f, 0.f};
    float pb[4] = {0.f, 0.f, 0.f, 0.f};
#pragma unroll
    for (int nt = 0; nt < NT; nt++) {
        int col = nt * 16 + l15;
        float bv = bias[col];
        float w0 = Wlin[col];
        float w1 = Wlin[128 + col];
#pragma unroll
        for (int reg = 0; reg < 4; reg++) {
            float v = acc[nt][reg] + bv;
            pa[reg] += v * w0;
            pb[reg] += v * w1;
        }
    }
#pragma unroll
    for (int off = 1; off < 16; off <<= 1) {
#pragma unroll
        for (int reg = 0; reg < 4; reg++) {
            pa[reg] += __shfl_xor(pa[reg], off, 64);
            pb[reg] += __shfl_xor(pb[reg], off, 64);
        }
    }
    if (l15 == 0) {
        int mb = m0 + quad * 4;
#pragma unroll
        for (int reg = 0; reg < 4; reg++) {
            int m = mb + reg;
            if (m < NN) { sa[m] = pa[reg]; sb[m] = pb[reg]; }
        }
    }
}

// ---------------- pair scorer: out[p] = sigmoid(sa[a] + sb[b] + blin) ----------------
__global__ void k_pairs(const float* __restrict__ sa, const float* __restrict__ sb,
                        const int* __restrict__ mask, const float* __restrict__ blin,
                        float* __restrict__ out) {
    int p = blockIdx.x * 256 + threadIdx.x;
    if (p >= NP) return;
    int2 m = ((const int2*)mask)[p];
    float v = sa[m.x] + sb[m.y] + blin[0];
    out[p] = 1.0f / (1.0f + __expf(-v));
}

extern "C" void kernel_launch(void* const* d_in, const int* in_sizes, int n_in,
                              void* d_out, int out_size, void* d_ws, size_t ws_size,
                              hipStream_t stream) {
    const float* x    = (const float*)d_in[0];   // [50000,128]
    const int*   ei   = (const int*)  d_in[1];   // [2,600000]
    const int*   mask = (const int*)  d_in[2];   // [200000,2]
    const float* W1l  = (const float*)d_in[3];   // [128,256]
    const float* b1l  = (const float*)d_in[4];   // [256]
    const float* W1r  = (const float*)d_in[5];   // [128,256]
    const float* W2l  = (const float*)d_in[6];   // [256,128]
    const float* b2l  = (const float*)d_in[7];   // [128]
    const float* W2r  = (const float*)d_in[8];   // [256,128]
    const float* Wlin = (const float*)d_in[9];   // [256,1]
    const float* blin = (const float*)d_in[10];  // [1]
    float* out = (float*)d_out;                  // [200000,1]

    const int* src = ei;
    const int* dst = ei + NE;

    char* ws = (char*)d_ws;
    int*    deg    = (int*)(ws);                             // 200 KB
    int*    rowptr = (int*)(ws + (size_t)1 * (1 << 20));
    int*    cursor = (int*)(ws + (size_t)2 * (1 << 20));
    int*    ssrc   = (int*)(ws + (size_t)3 * (1 << 20));     // 2.4 MB -> ends at 5.4 MB
    int*    excl   = (int*)(ws + (size_t)6 * (1 << 20));     // 200 KB
    int*    bsum   = (int*)(ws + (size_t)7 * (1 << 20));     // 196 B
    ushort* Bp1    = (ushort*)(ws + (size_t)8 * (1 << 20));  // 128 KB
    ushort* Bp2    = (ushort*)(ws + (size_t)9 * (1 << 20));  // 128 KB
    float*  sa     = (float*)(ws + (size_t)10 * (1 << 20));  // 200 KB
    float*  sb     = (float*)(ws + (size_t)11 * (1 << 20));  // 200 KB
    uint*   A1u    = (uint*)(ws + (size_t)12 * (1 << 20));   // [50000,256] bf16 = 25.6 MB
    uint*   A2u    = (uint*)(ws + (size_t)38 * (1 << 20));   // [50000,512] bf16 = 51.2 MB

    hipMemsetAsync(deg, 0, (size_t)NN * 4, stream);

    k_pre  <<<(T_B2 + 255) / 256, 256, 0, stream>>>(x, A1u, dst, deg,
                                                    W1l, W1r, Bp1, W2l, W2r, Bp2);
    k_scan1<<<NB_SCAN, 1024, 0, stream>>>(deg, excl, bsum);
    k_scan2<<<1, 64, 0, stream>>>(bsum);
    k_scan3<<<NB_SCAN, 1024, 0, stream>>>(excl, bsum, rowptr, cursor);
    k_fill <<<(NE + 255) / 256, 256, 0, stream>>>(src, dst, cursor, ssrc);

    k_agg1 <<<NN / 4, 256, 0, stream>>>(A1u, rowptr, ssrc);
    k_gemm1<<<(NN + 63) / 64, 256, 0, stream>>>((const ushort*)A1u, Bp1, b1l,
                                                (ushort*)A2u);
    k_agg2 <<<NN / 4, 256, 0, stream>>>(A2u, rowptr, ssrc);
    k_gemm2<<<(NN + 63) / 64, 256, 0, stream>>>((const ushort*)A2u, Bp2, b2l, Wlin,
                                                sa, sb);
    k_pairs<<<(NP + 255) / 256, 256, 0, stream>>>(sa, sb, mask, blin, out);
}

// Round 6
// 308.304 us; speedup vs baseline: 9.9911x; 1.0139x over previous
//
#include <hip/hip_runtime.h>
#include <math.h>

#define NN 50000
#define NE 600000
#define NP 200000
#define NB_SCAN 49  // ceil(NN / 1024)

typedef unsigned int uint;
typedef unsigned short ushort;
typedef __attribute__((ext_vector_type(8))) short bf16x8;
typedef __attribute__((ext_vector_type(4))) float f32x4;

// ---- bf16 helpers (RNE) ----
__device__ __forceinline__ ushort f2bf(float f) {
    uint u = __float_as_uint(f);
    uint r = (u + 0x7FFFu + ((u >> 16) & 1u)) >> 16;
    return (ushort)r;
}
__device__ __forceinline__ float bf2f(uint lo16) {
    return __uint_as_float(lo16 << 16);
}

__device__ __forceinline__ int wave_iscan(int v, int lane) {
#pragma unroll
    for (int off = 1; off < 64; off <<= 1) {
        int t = __shfl_up(v, off, 64);
        if (lane >= off) v += t;
    }
    return v;
}

// ---- W swizzle into MFMA B-operand layout (bf16), device helper ----
// Bp[((ct*(N/16)+nt)*64 + lane)*8 + j] = Wcat[ct*32 + (lane>>4)*8 + j][nt*16 + (lane&15)]
template <int K, int N>
__device__ __forceinline__ void prepB_one(int idx, const float* __restrict__ Wt,
                                          const float* __restrict__ Wb,
                                          ushort* __restrict__ Bp) {
    int lane = idx & 63;
    int nt = (idx >> 6) % (N / 16);
    int ct = idx / (64 * (N / 16));
    int n = nt * 16 + (lane & 15);
    int kb = ct * 32 + (lane >> 4) * 8;
#pragma unroll
    for (int j = 0; j < 8; j++) {
        int k = kb + j;
        float w = (k < K / 2) ? Wt[(size_t)k * N + n] : Wb[(size_t)(k - K / 2) * N + n];
        Bp[(size_t)idx * 8 + j] = f2bf(w);
    }
}

// ---------------- fused prologue: deg histogram + x->bf16 + W swizzles ----------------
#define T_PREP (NN * 64)
#define T_DEG  (T_PREP + NE)
#define T_B1   (T_DEG + 8192)
#define T_B2   (T_B1 + 8192)
__global__ void k_pre(const float* __restrict__ x, uint* __restrict__ A1u,
                      const int* __restrict__ dst, int* __restrict__ deg,
                      const float* __restrict__ W1l, const float* __restrict__ W1r,
                      ushort* __restrict__ Bp1,
                      const float* __restrict__ W2l, const float* __restrict__ W2r,
                      ushort* __restrict__ Bp2) {
    int t = blockIdx.x * 256 + threadIdx.x;
    if (t < T_PREP) {
        int n = t >> 6, c2 = t & 63;
        float2 v = *(const float2*)(x + (size_t)n * 128 + c2 * 2);
        A1u[(size_t)n * 128 + 64 + c2] = (uint)f2bf(v.x) | ((uint)f2bf(v.y) << 16);
    } else if (t < T_DEG) {
        atomicAdd(deg + dst[t - T_PREP], 1);
    } else if (t < T_B1) {
        prepB_one<256, 256>(t - T_DEG, W1l, W1r, Bp1);
    } else if (t < T_B2) {
        prepB_one<512, 128>(t - T_B1, W2l, W2r, Bp2);
    }
}

// ---------------- 3-phase grid-wide exclusive scan of deg ----------------
__global__ __launch_bounds__(1024) void k_scan1(const int* __restrict__ deg,
                                                int* __restrict__ excl,
                                                int* __restrict__ bsum) {
    int tid = threadIdx.x;
    int i = blockIdx.x * 1024 + tid;
    int lane = tid & 63, wid = tid >> 6;
    int v = (i < NN) ? deg[i] : 0;
    int incl = wave_iscan(v, lane);
    __shared__ int wt[16];
    if (lane == 63) wt[wid] = incl;
    __syncthreads();
    if (tid < 16) {
        int w = wt[tid];
#pragma unroll
        for (int off = 1; off < 16; off <<= 1) {
            int t = __shfl_up(w, off, 64);
            if (tid >= off) w += t;
        }
        wt[tid] = w;
    }
    __syncthreads();
    int base = (wid > 0) ? wt[wid - 1] : 0;
    if (i < NN) excl[i] = incl - v + base;
    if (tid == 0) bsum[blockIdx.x] = wt[15];
}

__global__ void k_scan2(int* __restrict__ bsum) {
    int lane = threadIdx.x;
    int v = (lane < NB_SCAN) ? bsum[lane] : 0;
    int incl = wave_iscan(v, lane);
    if (lane < NB_SCAN) bsum[lane] = incl - v;
}

__global__ __launch_bounds__(1024) void k_scan3(const int* __restrict__ excl,
                                                const int* __restrict__ bsum,
                                                int* __restrict__ rowptr,
                                                int* __restrict__ cursor) {
    int i = blockIdx.x * 1024 + threadIdx.x;
    if (i < NN) {
        int v = excl[i] + bsum[blockIdx.x];
        rowptr[i] = v;
        cursor[i] = v;
    }
    if (i == 0) rowptr[NN] = NE;
}

// ---------------- edge placement: ssrc sorted by dst ----------------
__global__ void k_fill(const int* __restrict__ src, const int* __restrict__ dst,
                       int* __restrict__ cursor, int* __restrict__ ssrc) {
    int e = blockIdx.x * 256 + threadIdx.x;
    if (e >= NE) return;
    int d = dst[e];
    int pos = atomicAdd(cursor + d, 1);
    ssrc[pos] = src[e];
}

// ---------------- gather-mean of x(bf16) -> A1 left half; 4 edges in flight ----------------
__global__ void k_agg1(uint* __restrict__ A1u, const int* __restrict__ rowptr,
                       const int* __restrict__ ssrc) {
    int t = blockIdx.x * 256 + threadIdx.x;
    int n = t >> 6;
    if (n >= NN) return;
    int lane = t & 63;
    int r0 = rowptr[n], r1 = rowptr[n + 1];
    float ax0 = 0.f, ay0 = 0.f, ax1 = 0.f, ay1 = 0.f;
    float ax2 = 0.f, ay2 = 0.f, ax3 = 0.f, ay3 = 0.f;
    int e = r0;
    for (; e + 4 <= r1; e += 4) {
        int s0 = ssrc[e], s1 = ssrc[e + 1], s2 = ssrc[e + 2], s3 = ssrc[e + 3];
        uint v0 = A1u[(size_t)s0 * 128 + 64 + lane];
        uint v1 = A1u[(size_t)s1 * 128 + 64 + lane];
        uint v2 = A1u[(size_t)s2 * 128 + 64 + lane];
        uint v3 = A1u[(size_t)s3 * 128 + 64 + lane];
        ax0 += bf2f(v0 & 0xffffu); ay0 += bf2f(v0 >> 16);
        ax1 += bf2f(v1 & 0xffffu); ay1 += bf2f(v1 >> 16);
        ax2 += bf2f(v2 & 0xffffu); ay2 += bf2f(v2 >> 16);
        ax3 += bf2f(v3 & 0xffffu); ay3 += bf2f(v3 >> 16);
    }
    for (; e < r1; e++) {
        int s = ssrc[e];
        uint v = A1u[(size_t)s * 128 + 64 + lane];
        ax0 += bf2f(v & 0xffffu); ay0 += bf2f(v >> 16);
    }
    float ax = (ax0 + ax1) + (ax2 + ax3);
    float ay = (ay0 + ay1) + (ay2 + ay3);
    float sc = 1.0f / fmaxf((float)(r1 - r0), 1.0f);
    A1u[(size_t)n * 128 + lane] = (uint)f2bf(ax * sc) | ((uint)f2bf(ay * sc) << 16);
}

// ---------------- gather-mean of h1(bf16, A2 right) -> A2 left; 8 edges in flight --------
__global__ void k_agg2(uint* __restrict__ A2u, const int* __restrict__ rowptr,
                       const int* __restrict__ ssrc) {
    int t = blockIdx.x * 256 + threadIdx.x;
    int n = t >> 6;
    if (n >= NN) return;
    int lane = t & 63;
    int r0 = rowptr[n], r1 = rowptr[n + 1];
    float a0[4] = {0.f, 0.f, 0.f, 0.f};
    float a1[4] = {0.f, 0.f, 0.f, 0.f};
    float a2[4] = {0.f, 0.f, 0.f, 0.f};
    float a3[4] = {0.f, 0.f, 0.f, 0.f};
    int e = r0;
    for (; e + 8 <= r1; e += 8) {
        uint2 v0 = *(const uint2*)(A2u + (size_t)ssrc[e]     * 256 + 128 + lane * 2);
        uint2 v1 = *(const uint2*)(A2u + (size_t)ssrc[e + 1] * 256 + 128 + lane * 2);
        uint2 v2 = *(const uint2*)(A2u + (size_t)ssrc[e + 2] * 256 + 128 + lane * 2);
        uint2 v3 = *(const uint2*)(A2u + (size_t)ssrc[e + 3] * 256 + 128 + lane * 2);
        uint2 v4 = *(const uint2*)(A2u + (size_t)ssrc[e + 4] * 256 + 128 + lane * 2);
        uint2 v5 = *(const uint2*)(A2u + (size_t)ssrc[e + 5] * 256 + 128 + lane * 2);
        uint2 v6 = *(const uint2*)(A2u + (size_t)ssrc[e + 6] * 256 + 128 + lane * 2);
        uint2 v7 = *(const uint2*)(A2u + (size_t)ssrc[e + 7] * 256 + 128 + lane * 2);
        a0[0] += bf2f(v0.x & 0xffffu); a0[1] += bf2f(v0.x >> 16);
        a0[2] += bf2f(v0.y & 0xffffu); a0[3] += bf2f(v0.y >> 16);
        a1[0] += bf2f(v1.x & 0xffffu); a1[1] += bf2f(v1.x >> 16);
        a1[2] += bf2f(v1.y & 0xffffu); a1[3] += bf2f(v1.y >> 16);
        a2[0] += bf2f(v2.x & 0xffffu); a2[1] += bf2f(v2.x >> 16);
        a2[2] += bf2f(v2.y & 0xffffu); a2[3] += bf2f(v2.y >> 16);
        a3[0] += bf2f(v3.x & 0xffffu); a3[1] += bf2f(v3.x >> 16);
        a3[2] += bf2f(v3.y & 0xffffu); a3[3] += bf2f(v3.y >> 16);
        a0[0] += bf2f(v4.x & 0xffffu); a0[1] += bf2f(v4.x >> 16);
        a0[2] += bf2f(v4.y & 0xffffu); a0[3] += bf2f(v4.y >> 16);
        a1[0] += bf2f(v5.x & 0xffffu); a1[1] += bf2f(v5.x >> 16);
        a1[2] += bf2f(v5.y & 0xffffu); a1[3] += bf2f(v5.y >> 16);
        a2[0] += bf2f(v6.x & 0xffffu); a2[1] += bf2f(v6.x >> 16);
        a2[2] += bf2f(v6.y & 0xffffu); a2[3] += bf2f(v6.y >> 16);
        a3[0] += bf2f(v7.x & 0xffffu); a3[1] += bf2f(v7.x >> 16);
        a3[2] += bf2f(v7.y & 0xffffu); a3[3] += bf2f(v7.y >> 16);
    }
    for (; e < r1; e++) {
        int s = ssrc[e];
        uint2 v = *(const uint2*)(A2u + (size_t)s * 256 + 128 + lane * 2);
        a0[0] += bf2f(v.x & 0xffffu); a0[1] += bf2f(v.x >> 16);
        a0[2] += bf2f(v.y & 0xffffu); a0[3] += bf2f(v.y >> 16);
    }
    float sc = 1.0f / fmaxf((float)(r1 - r0), 1.0f);
    float r00 = ((a0[0] + a1[0]) + (a2[0] + a3[0])) * sc;
    float r01 = ((a0[1] + a1[1]) + (a2[1] + a3[1])) * sc;
    float r10 = ((a0[2] + a1[2]) + (a2[2] + a3[2])) * sc;
    float r11 = ((a0[3] + a1[3]) + (a2[3] + a3[3])) * sc;
    uint2 o;
    o.x = (uint)f2bf(r00) | ((uint)f2bf(r01) << 16);
    o.y = (uint)f2bf(r10) | ((uint)f2bf(r11) << 16);
    *(uint2*)(A2u + (size_t)n * 256 + lane * 2) = o;
}

// ---------------- layer-1 GEMM: A2 right half = relu(A1@[W1l;W1r] + b1l), bf16 --------
// R=2 row-tiles per wave (32 rows): each B-frag load feeds 2 MFMAs -> B L2 traffic
// halves vs R=1. Block = 128 thr (2 waves, 64 rows), grid 782 (~3 blocks/CU).
// Layouts (m89/m91-verified): A-frag A[m=lane&15][k=quad*8+j]; C/D col=lane&15, row=quad*4+reg.
__global__ __launch_bounds__(128) void k_gemm1(const ushort* __restrict__ A,
                                               const ushort* __restrict__ Bp,
                                               const float* __restrict__ bias,
                                               ushort* __restrict__ out) {
    const int K = 256, NT = 16;
    int wave = threadIdx.x >> 6;
    int lane = threadIdx.x & 63;
    int quad = lane >> 4;
    int l15 = lane & 15;
    int m0 = blockIdx.x * 64 + wave * 32;
    int r0 = m0 + l15;       if (r0 >= NN) r0 = NN - 1;
    int r1 = m0 + 16 + l15;  if (r1 >= NN) r1 = NN - 1;
    f32x4 acc0[NT], acc1[NT];
#pragma unroll
    for (int i = 0; i < NT; i++) {
        acc0[i] = (f32x4){0.f, 0.f, 0.f, 0.f};
        acc1[i] = (f32x4){0.f, 0.f, 0.f, 0.f};
    }
    const bf16x8* bp = (const bf16x8*)Bp;
#pragma unroll
    for (int ct = 0; ct < K / 32; ct++) {
        bf16x8 a0 = *(const bf16x8*)(A + (size_t)r0 * K + ct * 32 + quad * 8);
        bf16x8 a1 = *(const bf16x8*)(A + (size_t)r1 * K + ct * 32 + quad * 8);
#pragma unroll
        for (int nt = 0; nt < NT; nt++) {
            bf16x8 b = bp[(ct * NT + nt) * 64 + lane];
            acc0[nt] = __builtin_amdgcn_mfma_f32_16x16x32_bf16(a0, b, acc0[nt], 0, 0, 0);
            acc1[nt] = __builtin_amdgcn_mfma_f32_16x16x32_bf16(a1, b, acc1[nt], 0, 0, 0);
        }
    }
#pragma unroll
    for (int rt = 0; rt < 2; rt++) {
        int mb = m0 + rt * 16 + quad * 4;
#pragma unroll
        for (int nt = 0; nt < NT; nt++) {
            int col = nt * 16 + l15;
            float bv = bias[col];
#pragma unroll
            for (int reg = 0; reg < 4; reg++) {
                int m = mb + reg;
                if (m < NN) {
                    float v = (rt ? acc1[nt][reg] : acc0[nt][reg]) + bv;
                    out[(size_t)m * 512 + 256 + col] = f2bf(v > 0.f ? v : 0.f);
                }
            }
        }
    }
}

// ---------------- layer-2 GEMM + fused Wlin dot: sa/sb per node, h2 never stored -------
// Same R=2 structure. sa[m] = (A2[m]@W2cat + b2l) . Wlin[0:128]; sb = . Wlin[128:256]
__global__ __launch_bounds__(128) void k_gemm2(const ushort* __restrict__ A,
                                               const ushort* __restrict__ Bp,
                                               const float* __restrict__ bias,
                                               const float* __restrict__ Wlin,
                                               float* __restrict__ sa,
                                               float* __restrict__ sb) {
    const int K = 512, NT = 8;
    int wave = threadIdx.x >> 6;
    int lane = threadIdx.x & 63;
    int quad = lane >> 4;
    int l15 = lane & 15;
    int m0 = blockIdx.x * 64 + wave * 32;
    int r0 = m0 + l15;       if (r0 >= NN) r0 = NN - 1;
    int r1 = m0 + 16 + l15;  if (r1 >= NN) r1 = NN - 1;
    f32x4 acc0[NT], acc1[NT];
#pragma unroll
    for (int i = 0; i < NT; i++) {
        acc0[i] = (f32x4){0.f, 0.f, 0.f, 0.f};
        acc1[i] = (f32x4){0.f, 0.f, 0.f, 0.f};
    }
    const bf16x8* bp = (const bf16x8*)Bp;
#pragma unroll
    for (int ct = 0; ct < K / 32; ct++) {
        bf16x8 a0 = *(const bf16x8*)(A + (size_t)r0 * K + ct * 32 + quad * 8);
        bf16x8 a1 = *(const bf16x8*)(A + (size_t)r1 * K + ct * 32 + quad * 8);
#pragma unroll
        for (int nt = 0; nt < NT; nt++) {
            bf16x8 b = bp[(ct * NT + nt) * 64 + lane];
            acc0[nt] = __builtin_amdgcn_mfma_f32_16x16x32_bf16(a0, b, acc0[nt], 0, 0, 0);
            acc1[nt] = __builtin_amdgcn_mfma_f32_16x16x32_bf16(a1, b, acc1[nt], 0, 0, 0);
        }
    }
    float pa[2][4] = {{0.f, 0.f, 0.f, 0.f}, {0.f, 0.f, 0.f, 0.f}};
    float pb[2][4] = {{0.f, 0.f, 0.f, 0.f}, {0.f, 0.f, 0.f, 0.f}};
#pragma unroll
    for (int nt = 0; nt < NT; nt++) {
        int col = nt * 16 + l15;
        float bv = bias[col];
        float w0 = Wlin[col];
        float w1 = Wlin[128 + col];
#pragma unroll
        for (int reg = 0; reg < 4; reg++) {
            float v0 = acc0[nt][reg] + bv;
            float v1 = acc1[nt][reg] + bv;
            pa[0][reg] += v0 * w0;  pb[0][reg] += v0 * w1;
            pa[1][reg] += v1 * w0;  pb[1][reg] += v1 * w1;
        }
    }
#pragma unroll
    for (int off = 1; off < 16; off <<= 1) {
#pragma unroll
        for (int rt = 0; rt < 2; rt++) {
#pragma unroll
            for (int reg = 0; reg < 4; reg++) {
                pa[rt][reg] += __shfl_xor(pa[rt][reg], off, 64);
                pb[rt][reg] += __shfl_xor(pb[rt][reg], off, 64);
            }
        }
    }
    if (l15 == 0) {
#pragma unroll
        for (int rt = 0; rt < 2; rt++) {
            int mb = m0 + rt * 16 + quad * 4;
#pragma unroll
            for (int reg = 0; reg < 4; reg++) {
                int m = mb + reg;
                if (m < NN) { sa[m] = pa[rt][reg]; sb[m] = pb[rt][reg]; }
            }
        }
    }
}

// ---------------- pair scorer: out[p] = sigmoid(sa[a] + sb[b] + blin) ----------------
__global__ void k_pairs(const float* __restrict__ sa, const float* __restrict__ sb,
                        const int* __restrict__ mask, const float* __restrict__ blin,
                        float* __restrict__ out) {
    int p = blockIdx.x * 256 + threadIdx.x;
    if (p >= NP) return;
    int2 m = ((const int2*)mask)[p];
    float v = sa[m.x] + sb[m.y] + blin[0];
    out[p] = 1.0f / (1.0f + __expf(-v));
}

extern "C" void kernel_launch(void* const* d_in, const int* in_sizes, int n_in,
                              void* d_out, int out_size, void* d_ws, size_t ws_size,
                              hipStream_t stream) {
    const float* x    = (const float*)d_in[0];   // [50000,128]
    const int*   ei   = (const int*)  d_in[1];   // [2,600000]
    const int*   mask = (const int*)  d_in[2];   // [200000,2]
    const float* W1l  = (const float*)d_in[3];   // [128,256]
    const float* b1l  = (const float*)d_in[4];   // [256]
    const float* W1r  = (const float*)d_in[5];   // [128,256]
    const float* W2l  = (const float*)d_in[6];   // [256,128]
    const float* b2l  = (const float*)d_in[7];   // [128]
    const float* W2r  = (const float*)d_in[8];   // [256,128]
    const float* Wlin = (const float*)d_in[9];   // [256,1]
    const float* blin = (const float*)d_in[10];  // [1]
    float* out = (float*)d_out;                  // [200000,1]

    const int* src = ei;
    const int* dst = ei + NE;

    char* ws = (char*)d_ws;
    int*    deg    = (int*)(ws);                             // 200 KB
    int*    rowptr = (int*)(ws + (size_t)1 * (1 << 20));
    int*    cursor = (int*)(ws + (size_t)2 * (1 << 20));
    int*    ssrc   = (int*)(ws + (size_t)3 * (1 << 20));     // 2.4 MB
    int*    excl   = (int*)(ws + (size_t)6 * (1 << 20));     // 200 KB
    int*    bsum   = (int*)(ws + (size_t)7 * (1 << 20));     // 196 B
    ushort* Bp1    = (ushort*)(ws + (size_t)8 * (1 << 20));  // 128 KB
    ushort* Bp2    = (ushort*)(ws + (size_t)9 * (1 << 20));  // 128 KB
    float*  sa     = (float*)(ws + (size_t)10 * (1 << 20));  // 200 KB
    float*  sb     = (float*)(ws + (size_t)11 * (1 << 20));  // 200 KB
    uint*   A1u    = (uint*)(ws + (size_t)12 * (1 << 20));   // [50000,256] bf16 = 25.6 MB
    uint*   A2u    = (uint*)(ws + (size_t)38 * (1 << 20));   // [50000,512] bf16 = 51.2 MB

    hipMemsetAsync(deg, 0, (size_t)NN * 4, stream);

    k_pre  <<<(T_B2 + 255) / 256, 256, 0, stream>>>(x, A1u, dst, deg,
                                                    W1l, W1r, Bp1, W2l, W2r, Bp2);
    k_scan1<<<NB_SCAN, 1024, 0, stream>>>(deg, excl, bsum);
    k_scan2<<<1, 64, 0, stream>>>(bsum);
    k_scan3<<<NB_SCAN, 1024, 0, stream>>>(excl, bsum, rowptr, cursor);
    k_fill <<<(NE + 255) / 256, 256, 0, stream>>>(src, dst, cursor, ssrc);

    k_agg1 <<<NN / 4, 256, 0, stream>>>(A1u, rowptr, ssrc);
    k_gemm1<<<(NN + 63) / 64, 128, 0, stream>>>((const ushort*)A1u, Bp1, b1l,
                                                (ushort*)A2u);
    k_agg2 <<<NN / 4, 256, 0, stream>>>(A2u, rowptr, ssrc);
    k_gemm2<<<(NN + 63) / 64, 128, 0, stream>>>((const ushort*)A2u, Bp2, b2l, Wlin,
                                                sa, sb);
    k_pairs<<<(NP + 255) / 256, 256, 0, stream>>>(sa, sb, mask, blin, out);
}

// Round 7
// 299.774 us; speedup vs baseline: 10.2754x; 1.0285x over previous
//
#include <hip/hip_runtime.h>
#include <math.h>

#define NN 50000
#define NE 600000
#define NP 200000
#define NB_SCAN 49  // ceil(NN / 1024)

typedef unsigned int uint;
typedef unsigned short ushort;
typedef __attribute__((ext_vector_type(8))) short bf16x8;
typedef __attribute__((ext_vector_type(4))) float f32x4;

// ---- bf16 helpers (RNE) ----
__device__ __forceinline__ ushort f2bf(float f) {
    uint u = __float_as_uint(f);
    uint r = (u + 0x7FFFu + ((u >> 16) & 1u)) >> 16;
    return (ushort)r;
}
__device__ __forceinline__ float bf2f(uint lo16) {
    return __uint_as_float(lo16 << 16);
}

__device__ __forceinline__ int wave_iscan(int v, int lane) {
#pragma unroll
    for (int off = 1; off < 64; off <<= 1) {
        int t = __shfl_up(v, off, 64);
        if (lane >= off) v += t;
    }
    return v;
}

// ---- W swizzle into MFMA B-operand layout (bf16), device helper ----
// Bp[((ct*(N/16)+nt)*64 + lane)*8 + j] = Wcat[ct*32 + (lane>>4)*8 + j][nt*16 + (lane&15)]
template <int K, int N>
__device__ __forceinline__ void prepB_one(int idx, const float* __restrict__ Wt,
                                          const float* __restrict__ Wb,
                                          ushort* __restrict__ Bp) {
    int lane = idx & 63;
    int nt = (idx >> 6) % (N / 16);
    int ct = idx / (64 * (N / 16));
    int n = nt * 16 + (lane & 15);
    int kb = ct * 32 + (lane >> 4) * 8;
#pragma unroll
    for (int j = 0; j < 8; j++) {
        int k = kb + j;
        float w = (k < K / 2) ? Wt[(size_t)k * N + n] : Wb[(size_t)(k - K / 2) * N + n];
        Bp[(size_t)idx * 8 + j] = f2bf(w);
    }
}

// ---------------- fused prologue: deg histogram + x->bf16 + W swizzles ----------------
#define T_PREP (NN * 64)
#define T_DEG  (T_PREP + NE)
#define T_B1   (T_DEG + 8192)
#define T_B2   (T_B1 + 8192)
__global__ void k_pre(const float* __restrict__ x, uint* __restrict__ A1u,
                      const int* __restrict__ dst, int* __restrict__ deg,
                      const float* __restrict__ W1l, const float* __restrict__ W1r,
                      ushort* __restrict__ Bp1,
                      const float* __restrict__ W2l, const float* __restrict__ W2r,
                      ushort* __restrict__ Bp2) {
    int t = blockIdx.x * 256 + threadIdx.x;
    if (t < T_PREP) {
        int n = t >> 6, c2 = t & 63;
        float2 v = *(const float2*)(x + (size_t)n * 128 + c2 * 2);
        A1u[(size_t)n * 128 + 64 + c2] = (uint)f2bf(v.x) | ((uint)f2bf(v.y) << 16);
    } else if (t < T_DEG) {
        atomicAdd(deg + dst[t - T_PREP], 1);
    } else if (t < T_B1) {
        prepB_one<256, 256>(t - T_DEG, W1l, W1r, Bp1);
    } else if (t < T_B2) {
        prepB_one<512, 128>(t - T_B1, W2l, W2r, Bp2);
    }
}

// ---------------- 3-phase grid-wide exclusive scan of deg ----------------
__global__ __launch_bounds__(1024) void k_scan1(const int* __restrict__ deg,
                                                int* __restrict__ excl,
                                                int* __restrict__ bsum) {
    int tid = threadIdx.x;
    int i = blockIdx.x * 1024 + tid;
    int lane = tid & 63, wid = tid >> 6;
    int v = (i < NN) ? deg[i] : 0;
    int incl = wave_iscan(v, lane);
    __shared__ int wt[16];
    if (lane == 63) wt[wid] = incl;
    __syncthreads();
    if (tid < 16) {
        int w = wt[tid];
#pragma unroll
        for (int off = 1; off < 16; off <<= 1) {
            int t = __shfl_up(w, off, 64);
            if (tid >= off) w += t;
        }
        wt[tid] = w;
    }
    __syncthreads();
    int base = (wid > 0) ? wt[wid - 1] : 0;
    if (i < NN) excl[i] = incl - v + base;
    if (tid == 0) bsum[blockIdx.x] = wt[15];
}

__global__ void k_scan2(int* __restrict__ bsum) {
    int lane = threadIdx.x;
    int v = (lane < NB_SCAN) ? bsum[lane] : 0;
    int incl = wave_iscan(v, lane);
    if (lane < NB_SCAN) bsum[lane] = incl - v;
}

__global__ __launch_bounds__(1024) void k_scan3(const int* __restrict__ excl,
                                                const int* __restrict__ bsum,
                                                int* __restrict__ rowptr,
                                                int* __restrict__ cursor) {
    int i = blockIdx.x * 1024 + threadIdx.x;
    if (i < NN) {
        int v = excl[i] + bsum[blockIdx.x];
        rowptr[i] = v;
        cursor[i] = v;
    }
    if (i == 0) rowptr[NN] = NE;
}

// ---------------- edge placement: ssrc sorted by dst ----------------
__global__ void k_fill(const int* __restrict__ src, const int* __restrict__ dst,
                       int* __restrict__ cursor, int* __restrict__ ssrc) {
    int e = blockIdx.x * 256 + threadIdx.x;
    if (e >= NE) return;
    int d = dst[e];
    int pos = atomicAdd(cursor + d, 1);
    ssrc[pos] = src[e];
}

// ---------------- gather-mean of x(bf16) -> A1 left half; 4 edges in flight ----------------
__global__ void k_agg1(uint* __restrict__ A1u, const int* __restrict__ rowptr,
                       const int* __restrict__ ssrc) {
    int t = blockIdx.x * 256 + threadIdx.x;
    int n = t >> 6;
    if (n >= NN) return;
    int lane = t & 63;
    int r0 = rowptr[n], r1 = rowptr[n + 1];
    float ax0 = 0.f, ay0 = 0.f, ax1 = 0.f, ay1 = 0.f;
    float ax2 = 0.f, ay2 = 0.f, ax3 = 0.f, ay3 = 0.f;
    int e = r0;
    for (; e + 4 <= r1; e += 4) {
        int s0 = ssrc[e], s1 = ssrc[e + 1], s2 = ssrc[e + 2], s3 = ssrc[e + 3];
        uint v0 = A1u[(size_t)s0 * 128 + 64 + lane];
        uint v1 = A1u[(size_t)s1 * 128 + 64 + lane];
        uint v2 = A1u[(size_t)s2 * 128 + 64 + lane];
        uint v3 = A1u[(size_t)s3 * 128 + 64 + lane];
        ax0 += bf2f(v0 & 0xffffu); ay0 += bf2f(v0 >> 16);
        ax1 += bf2f(v1 & 0xffffu); ay1 += bf2f(v1 >> 16);
        ax2 += bf2f(v2 & 0xffffu); ay2 += bf2f(v2 >> 16);
        ax3 += bf2f(v3 & 0xffffu); ay3 += bf2f(v3 >> 16);
    }
    for (; e < r1; e++) {
        int s = ssrc[e];
        uint v = A1u[(size_t)s * 128 + 64 + lane];
        ax0 += bf2f(v & 0xffffu); ay0 += bf2f(v >> 16);
    }
    float ax = (ax0 + ax1) + (ax2 + ax3);
    float ay = (ay0 + ay1) + (ay2 + ay3);
    float sc = 1.0f / fmaxf((float)(r1 - r0), 1.0f);
    A1u[(size_t)n * 128 + lane] = (uint)f2bf(ax * sc) | ((uint)f2bf(ay * sc) << 16);
}

// ---------------- gather-mean of h1(bf16, A2 right) -> A2 left; 8 edges in flight --------
__global__ void k_agg2(uint* __restrict__ A2u, const int* __restrict__ rowptr,
                       const int* __restrict__ ssrc) {
    int t = blockIdx.x * 256 + threadIdx.x;
    int n = t >> 6;
    if (n >= NN) return;
    int lane = t & 63;
    int r0 = rowptr[n], r1 = rowptr[n + 1];
    float a0[4] = {0.f, 0.f, 0.f, 0.f};
    float a1[4] = {0.f, 0.f, 0.f, 0.f};
    float a2[4] = {0.f, 0.f, 0.f, 0.f};
    float a3[4] = {0.f, 0.f, 0.f, 0.f};
    int e = r0;
    for (; e + 8 <= r1; e += 8) {
        uint2 v0 = *(const uint2*)(A2u + (size_t)ssrc[e]     * 256 + 128 + lane * 2);
        uint2 v1 = *(const uint2*)(A2u + (size_t)ssrc[e + 1] * 256 + 128 + lane * 2);
        uint2 v2 = *(const uint2*)(A2u + (size_t)ssrc[e + 2] * 256 + 128 + lane * 2);
        uint2 v3 = *(const uint2*)(A2u + (size_t)ssrc[e + 3] * 256 + 128 + lane * 2);
        uint2 v4 = *(const uint2*)(A2u + (size_t)ssrc[e + 4] * 256 + 128 + lane * 2);
        uint2 v5 = *(const uint2*)(A2u + (size_t)ssrc[e + 5] * 256 + 128 + lane * 2);
        uint2 v6 = *(const uint2*)(A2u + (size_t)ssrc[e + 6] * 256 + 128 + lane * 2);
        uint2 v7 = *(const uint2*)(A2u + (size_t)ssrc[e + 7] * 256 + 128 + lane * 2);
        a0[0] += bf2f(v0.x & 0xffffu); a0[1] += bf2f(v0.x >> 16);
        a0[2] += bf2f(v0.y & 0xffffu); a0[3] += bf2f(v0.y >> 16);
        a1[0] += bf2f(v1.x & 0xffffu); a1[1] += bf2f(v1.x >> 16);
        a1[2] += bf2f(v1.y & 0xffffu); a1[3] += bf2f(v1.y >> 16);
        a2[0] += bf2f(v2.x & 0xffffu); a2[1] += bf2f(v2.x >> 16);
        a2[2] += bf2f(v2.y & 0xffffu); a2[3] += bf2f(v2.y >> 16);
        a3[0] += bf2f(v3.x & 0xffffu); a3[1] += bf2f(v3.x >> 16);
        a3[2] += bf2f(v3.y & 0xffffu); a3[3] += bf2f(v3.y >> 16);
        a0[0] += bf2f(v4.x & 0xffffu); a0[1] += bf2f(v4.x >> 16);
        a0[2] += bf2f(v4.y & 0xffffu); a0[3] += bf2f(v4.y >> 16);
        a1[0] += bf2f(v5.x & 0xffffu); a1[1] += bf2f(v5.x >> 16);
        a1[2] += bf2f(v5.y & 0xffffu); a1[3] += bf2f(v5.y >> 16);
        a2[0] += bf2f(v6.x & 0xffffu); a2[1] += bf2f(v6.x >> 16);
        a2[2] += bf2f(v6.y & 0xffffu); a2[3] += bf2f(v6.y >> 16);
        a3[0] += bf2f(v7.x & 0xffffu); a3[1] += bf2f(v7.x >> 16);
        a3[2] += bf2f(v7.y & 0xffffu); a3[3] += bf2f(v7.y >> 16);
    }
    for (; e < r1; e++) {
        int s = ssrc[e];
        uint2 v = *(const uint2*)(A2u + (size_t)s * 256 + 128 + lane * 2);
        a0[0] += bf2f(v.x & 0xffffu); a0[1] += bf2f(v.x >> 16);
        a0[2] += bf2f(v.y & 0xffffu); a0[3] += bf2f(v.y >> 16);
    }
    float sc = 1.0f / fmaxf((float)(r1 - r0), 1.0f);
    float r00 = ((a0[0] + a1[0]) + (a2[0] + a3[0])) * sc;
    float r01 = ((a0[1] + a1[1]) + (a2[1] + a3[1])) * sc;
    float r10 = ((a0[2] + a1[2]) + (a2[2] + a3[2])) * sc;
    float r11 = ((a0[3] + a1[3]) + (a2[3] + a3[3])) * sc;
    uint2 o;
    o.x = (uint)f2bf(r00) | ((uint)f2bf(r01) << 16);
    o.y = (uint)f2bf(r10) | ((uint)f2bf(r11) << 16);
    *(uint2*)(A2u + (size_t)n * 256 + lane * 2) = o;
}

// ---------------- layer-1 GEMM, N-split: A2 right = relu(A1@[W1l;W1r]+b1l) -------------
// Block = 256 thr (4 waves) covering 32 rows x 256 cols; wave owns cols [wave*64, +64)
// (4 nt) and 2 row-tiles. Grid 1563 -> 6252 waves (~6/SIMD). B read disjointly by waves.
// Layouts (m89/m91-verified): A-frag A[m=lane&15][k=quad*8+j]; C/D col=lane&15, row=quad*4+reg.
__global__ __launch_bounds__(256) void k_gemm1(const ushort* __restrict__ A,
                                               const ushort* __restrict__ Bp,
                                               const float* __restrict__ bias,
                                               ushort* __restrict__ out) {
    const int K = 256, NTW = 4;  // nt per wave
    int wave = threadIdx.x >> 6;
    int lane = threadIdx.x & 63;
    int quad = lane >> 4;
    int l15 = lane & 15;
    int mbase = blockIdx.x * 32;
    int r0 = mbase + l15;       if (r0 >= NN) r0 = NN - 1;
    int r1 = mbase + 16 + l15;  if (r1 >= NN) r1 = NN - 1;
    f32x4 acc0[NTW], acc1[NTW];
#pragma unroll
    for (int i = 0; i < NTW; i++) {
        acc0[i] = (f32x4){0.f, 0.f, 0.f, 0.f};
        acc1[i] = (f32x4){0.f, 0.f, 0.f, 0.f};
    }
    const bf16x8* bp = (const bf16x8*)Bp;
#pragma unroll
    for (int ct = 0; ct < K / 32; ct++) {
        bf16x8 a0 = *(const bf16x8*)(A + (size_t)r0 * K + ct * 32 + quad * 8);
        bf16x8 a1 = *(const bf16x8*)(A + (size_t)r1 * K + ct * 32 + quad * 8);
#pragma unroll
        for (int ntl = 0; ntl < NTW; ntl++) {
            int nt = wave * NTW + ntl;
            bf16x8 b = bp[(ct * 16 + nt) * 64 + lane];
            acc0[ntl] = __builtin_amdgcn_mfma_f32_16x16x32_bf16(a0, b, acc0[ntl], 0, 0, 0);
            acc1[ntl] = __builtin_amdgcn_mfma_f32_16x16x32_bf16(a1, b, acc1[ntl], 0, 0, 0);
        }
    }
#pragma unroll
    for (int rt = 0; rt < 2; rt++) {
        int mb = mbase + rt * 16 + quad * 4;
#pragma unroll
        for (int ntl = 0; ntl < NTW; ntl++) {
            int col = (wave * NTW + ntl) * 16 + l15;
            float bv = bias[col];
#pragma unroll
            for (int reg = 0; reg < 4; reg++) {
                int m = mb + reg;
                if (m < NN) {
                    float v = (rt ? acc1[ntl][reg] : acc0[ntl][reg]) + bv;
                    out[(size_t)m * 512 + 256 + col] = f2bf(v > 0.f ? v : 0.f);
                }
            }
        }
    }
}

// ---------------- layer-2 GEMM + fused Wlin dot, N-split ------------------------------
// Block = 32 rows x 128 cols; wave owns 2 nt (32 cols). Cross-wave LDS reduction for the
// per-row Wlin dots (each wave only sees 32 of 128 cols).
__global__ __launch_bounds__(256) void k_gemm2(const ushort* __restrict__ A,
                                               const ushort* __restrict__ Bp,
                                               const float* __restrict__ bias,
                                               const float* __restrict__ Wlin,
                                               float* __restrict__ sa,
                                               float* __restrict__ sb) {
    const int K = 512, NTW = 2;
    int wave = threadIdx.x >> 6;
    int lane = threadIdx.x & 63;
    int quad = lane >> 4;
    int l15 = lane & 15;
    int mbase = blockIdx.x * 32;
    int r0 = mbase + l15;       if (r0 >= NN) r0 = NN - 1;
    int r1 = mbase + 16 + l15;  if (r1 >= NN) r1 = NN - 1;
    f32x4 acc0[NTW], acc1[NTW];
#pragma unroll
    for (int i = 0; i < NTW; i++) {
        acc0[i] = (f32x4){0.f, 0.f, 0.f, 0.f};
        acc1[i] = (f32x4){0.f, 0.f, 0.f, 0.f};
    }
    const bf16x8* bp = (const bf16x8*)Bp;
#pragma unroll
    for (int ct = 0; ct < K / 32; ct++) {
        bf16x8 a0 = *(const bf16x8*)(A + (size_t)r0 * K + ct * 32 + quad * 8);
        bf16x8 a1 = *(const bf16x8*)(A + (size_t)r1 * K + ct * 32 + quad * 8);
#pragma unroll
        for (int ntl = 0; ntl < NTW; ntl++) {
            int nt = wave * NTW + ntl;
            bf16x8 b = bp[(ct * 8 + nt) * 64 + lane];
            acc0[ntl] = __builtin_amdgcn_mfma_f32_16x16x32_bf16(a0, b, acc0[ntl], 0, 0, 0);
            acc1[ntl] = __builtin_amdgcn_mfma_f32_16x16x32_bf16(a1, b, acc1[ntl], 0, 0, 0);
        }
    }
    // per-lane partial dots over this wave's 32 cols, rows (rt, quad, reg)
    float pa[2][4] = {{0.f, 0.f, 0.f, 0.f}, {0.f, 0.f, 0.f, 0.f}};
    float pb[2][4] = {{0.f, 0.f, 0.f, 0.f}, {0.f, 0.f, 0.f, 0.f}};
#pragma unroll
    for (int ntl = 0; ntl < NTW; ntl++) {
        int col = (wave * NTW + ntl) * 16 + l15;
        float bv = bias[col];
        float w0 = Wlin[col];
        float w1 = Wlin[128 + col];
#pragma unroll
        for (int reg = 0; reg < 4; reg++) {
            float v0 = acc0[ntl][reg] + bv;
            float v1 = acc1[ntl][reg] + bv;
            pa[0][reg] += v0 * w0;  pb[0][reg] += v0 * w1;
            pa[1][reg] += v1 * w0;  pb[1][reg] += v1 * w1;
        }
    }
    // intra-wave: reduce across 16 col-lanes (l15 bits)
#pragma unroll
    for (int off = 1; off < 16; off <<= 1) {
#pragma unroll
        for (int rt = 0; rt < 2; rt++) {
#pragma unroll
            for (int reg = 0; reg < 4; reg++) {
                pa[rt][reg] += __shfl_xor(pa[rt][reg], off, 64);
                pb[rt][reg] += __shfl_xor(pb[rt][reg], off, 64);
            }
        }
    }
    // cross-wave: LDS reduce (4 waves x 32 rows)
    __shared__ float reda[4][32], redb[4][32];
    if (l15 == 0) {
#pragma unroll
        for (int rt = 0; rt < 2; rt++) {
#pragma unroll
            for (int reg = 0; reg < 4; reg++) {
                int row = rt * 16 + quad * 4 + reg;
                reda[wave][row] = pa[rt][reg];
                redb[wave][row] = pb[rt][reg];
            }
        }
    }
    __syncthreads();
    if (threadIdx.x < 32) {
        int row = threadIdx.x;
        int m = mbase + row;
        if (m < NN) {
            sa[m] = (reda[0][row] + reda[1][row]) + (reda[2][row] + reda[3][row]);
            sb[m] = (redb[0][row] + redb[1][row]) + (redb[2][row] + redb[3][row]);
        }
    }
}

// ---------------- pair scorer: out[p] = sigmoid(sa[a] + sb[b] + blin) ----------------
__global__ void k_pairs(const float* __restrict__ sa, const float* __restrict__ sb,
                        const int* __restrict__ mask, const float* __restrict__ blin,
                        float* __restrict__ out) {
    int p = blockIdx.x * 256 + threadIdx.x;
    if (p >= NP) return;
    int2 m = ((const int2*)mask)[p];
    float v = sa[m.x] + sb[m.y] + blin[0];
    out[p] = 1.0f / (1.0f + __expf(-v));
}

extern "C" void kernel_launch(void* const* d_in, const int* in_sizes, int n_in,
                              void* d_out, int out_size, void* d_ws, size_t ws_size,
                              hipStream_t stream) {
    const float* x    = (const float*)d_in[0];   // [50000,128]
    const int*   ei   = (const int*)  d_in[1];   // [2,600000]
    const int*   mask = (const int*)  d_in[2];   // [200000,2]
    const float* W1l  = (const float*)d_in[3];   // [128,256]
    const float* b1l  = (const float*)d_in[4];   // [256]
    const float* W1r  = (const float*)d_in[5];   // [128,256]
    const float* W2l  = (const float*)d_in[6];   // [256,128]
    const float* b2l  = (const float*)d_in[7];   // [128]
    const float* W2r  = (const float*)d_in[8];   // [256,128]
    const float* Wlin = (const float*)d_in[9];   // [256,1]
    const float* blin = (const float*)d_in[10];  // [1]
    float* out = (float*)d_out;                  // [200000,1]

    const int* src = ei;
    const int* dst = ei + NE;

    char* ws = (char*)d_ws;
    int*    deg    = (int*)(ws);                             // 200 KB
    int*    rowptr = (int*)(ws + (size_t)1 * (1 << 20));
    int*    cursor = (int*)(ws + (size_t)2 * (1 << 20));
    int*    ssrc   = (int*)(ws + (size_t)3 * (1 << 20));     // 2.4 MB
    int*    excl   = (int*)(ws + (size_t)6 * (1 << 20));     // 200 KB
    int*    bsum   = (int*)(ws + (size_t)7 * (1 << 20));     // 196 B
    ushort* Bp1    = (ushort*)(ws + (size_t)8 * (1 << 20));  // 128 KB
    ushort* Bp2    = (ushort*)(ws + (size_t)9 * (1 << 20));  // 128 KB
    float*  sa     = (float*)(ws + (size_t)10 * (1 << 20));  // 200 KB
    float*  sb     = (float*)(ws + (size_t)11 * (1 << 20));  // 200 KB
    uint*   A1u    = (uint*)(ws + (size_t)12 * (1 << 20));   // [50000,256] bf16 = 25.6 MB
    uint*   A2u    = (uint*)(ws + (size_t)38 * (1 << 20));   // [50000,512] bf16 = 51.2 MB

    hipMemsetAsync(deg, 0, (size_t)NN * 4, stream);

    k_pre  <<<(T_B2 + 255) / 256, 256, 0, stream>>>(x, A1u, dst, deg,
                                                    W1l, W1r, Bp1, W2l, W2r, Bp2);
    k_scan1<<<NB_SCAN, 1024, 0, stream>>>(deg, excl, bsum);
    k_scan2<<<1, 64, 0, stream>>>(bsum);
    k_scan3<<<NB_SCAN, 1024, 0, stream>>>(excl, bsum, rowptr, cursor);
    k_fill <<<(NE + 255) / 256, 256, 0, stream>>>(src, dst, cursor, ssrc);

    k_agg1 <<<NN / 4, 256, 0, stream>>>(A1u, rowptr, ssrc);
    k_gemm1<<<(NN + 31) / 32, 256, 0, stream>>>((const ushort*)A1u, Bp1, b1l,
                                                (ushort*)A2u);
    k_agg2 <<<NN / 4, 256, 0, stream>>>(A2u, rowptr, ssrc);
    k_gemm2<<<(NN + 31) / 32, 256, 0, stream>>>((const ushort*)A2u, Bp2, b2l, Wlin,
                                                sa, sb);
    k_pairs<<<(NP + 255) / 256, 256, 0, stream>>>(sa, sb, mask, blin, out);
}

// Round 8
// 226.458 us; speedup vs baseline: 13.6021x; 1.3237x over previous
//
#include <hip/hip_runtime.h>
#include <math.h>

#define NN 50000
#define NE 600000
#define NP 200000
#define NB_SCAN 49  // ceil(NN / 1024)

typedef unsigned int uint;
typedef unsigned short ushort;
typedef __attribute__((ext_vector_type(8))) short bf16x8;
typedef __attribute__((ext_vector_type(4))) float f32x4;

// ---- bf16 helpers (RNE) ----
__device__ __forceinline__ ushort f2bf(float f) {
    uint u = __float_as_uint(f);
    uint r = (u + 0x7FFFu + ((u >> 16) & 1u)) >> 16;
    return (ushort)r;
}
__device__ __forceinline__ float bf2f(uint lo16) {
    return __uint_as_float(lo16 << 16);
}

__device__ __forceinline__ int wave_iscan(int v, int lane) {
#pragma unroll
    for (int off = 1; off < 64; off <<= 1) {
        int t = __shfl_up(v, off, 64);
        if (lane >= off) v += t;
    }
    return v;
}

// ---- W swizzle into MFMA B-operand layout (bf16) ----
// Bp[((ct*(N/16)+nt)*64 + lane)*8 + j] = Wcat[ct*32 + (lane>>4)*8 + j][nt*16 + (lane&15)]
template <int K, int N>
__device__ __forceinline__ void prepB_one(int idx, const float* __restrict__ Wt,
                                          const float* __restrict__ Wb,
                                          ushort* __restrict__ Bp) {
    int lane = idx & 63;
    int nt = (idx >> 6) % (N / 16);
    int ct = idx / (64 * (N / 16));
    int n = nt * 16 + (lane & 15);
    int kb = ct * 32 + (lane >> 4) * 8;
#pragma unroll
    for (int j = 0; j < 8; j++) {
        int k = kb + j;
        float w = (k < K / 2) ? Wt[(size_t)k * N + n] : Wb[(size_t)(k - K / 2) * N + n];
        Bp[(size_t)idx * 8 + j] = f2bf(w);
    }
}

// ---------------- fused prologue ----------------
// ranges: x->bf16 | deg histogram | Bp1 swizzle | pq vectors | cab scalars
// pq[0:256]=W2l@wa, pq[256:512]=W2l@wb, pq[512:768]=W2r@wa, pq[768:1024]=W2r@wb
// cab[0]=b2l.wa, cab[1]=b2l.wb
#define T_PREP (NN * 64)
#define T_DEG  (T_PREP + NE)
#define T_B1   (T_DEG + 8192)
#define T_PQ   (T_B1 + 1024)
#define T_CAB  (T_PQ + 2)
__global__ void k_pre(const float* __restrict__ x, uint* __restrict__ A1u,
                      const int* __restrict__ dst, int* __restrict__ deg,
                      const float* __restrict__ W1l, const float* __restrict__ W1r,
                      ushort* __restrict__ Bp1,
                      const float* __restrict__ W2l, const float* __restrict__ W2r,
                      const float* __restrict__ Wlin, const float* __restrict__ b2l,
                      float* __restrict__ pq, float* __restrict__ cab) {
    int t = blockIdx.x * 256 + threadIdx.x;
    if (t < T_PREP) {
        int n = t >> 6, c2 = t & 63;
        float2 v = *(const float2*)(x + (size_t)n * 128 + c2 * 2);
        A1u[(size_t)n * 128 + 64 + c2] = (uint)f2bf(v.x) | ((uint)f2bf(v.y) << 16);
    } else if (t < T_DEG) {
        atomicAdd(deg + dst[t - T_PREP], 1);
    } else if (t < T_B1) {
        prepB_one<256, 256>(t - T_DEG, W1l, W1r, Bp1);
    } else if (t < T_PQ) {
        int idx = t - T_B1;
        int vec = idx >> 8;          // 0..3
        int k = idx & 255;
        const float* W = (vec < 2) ? W2l : W2r;    // [256,128]
        const float* wl = Wlin + (vec & 1) * 128;  // wa or wb
        float s = 0.f;
#pragma unroll 4
        for (int j = 0; j < 128; j++) s += W[(size_t)k * 128 + j] * wl[j];
        pq[idx] = s;
    } else if (t < T_CAB) {
        int i = t - T_PQ;
        float s = 0.f;
        for (int j = 0; j < 128; j++) s += b2l[j] * Wlin[i * 128 + j];
        cab[i] = s;
    }
}

// ---------------- 3-phase grid-wide exclusive scan of deg ----------------
__global__ __launch_bounds__(1024) void k_scan1(const int* __restrict__ deg,
                                                int* __restrict__ excl,
                                                int* __restrict__ bsum) {
    int tid = threadIdx.x;
    int i = blockIdx.x * 1024 + tid;
    int lane = tid & 63, wid = tid >> 6;
    int v = (i < NN) ? deg[i] : 0;
    int incl = wave_iscan(v, lane);
    __shared__ int wt[16];
    if (lane == 63) wt[wid] = incl;
    __syncthreads();
    if (tid < 16) {
        int w = wt[tid];
#pragma unroll
        for (int off = 1; off < 16; off <<= 1) {
            int t = __shfl_up(w, off, 64);
            if (tid >= off) w += t;
        }
        wt[tid] = w;
    }
    __syncthreads();
    int base = (wid > 0) ? wt[wid - 1] : 0;
    if (i < NN) excl[i] = incl - v + base;
    if (tid == 0) bsum[blockIdx.x] = wt[15];
}

__global__ void k_scan2(int* __restrict__ bsum) {
    int lane = threadIdx.x;
    int v = (lane < NB_SCAN) ? bsum[lane] : 0;
    int incl = wave_iscan(v, lane);
    if (lane < NB_SCAN) bsum[lane] = incl - v;
}

__global__ __launch_bounds__(1024) void k_scan3(const int* __restrict__ excl,
                                                const int* __restrict__ bsum,
                                                int* __restrict__ rowptr,
                                                int* __restrict__ cursor) {
    int i = blockIdx.x * 1024 + threadIdx.x;
    if (i < NN) {
        int v = excl[i] + bsum[blockIdx.x];
        rowptr[i] = v;
        cursor[i] = v;
    }
    if (i == 0) rowptr[NN] = NE;
}

// ---------------- edge placement: ssrc sorted by dst ----------------
__global__ void k_fill(const int* __restrict__ src, const int* __restrict__ dst,
                       int* __restrict__ cursor, int* __restrict__ ssrc) {
    int e = blockIdx.x * 256 + threadIdx.x;
    if (e >= NE) return;
    int d = dst[e];
    int pos = atomicAdd(cursor + d, 1);
    ssrc[pos] = src[e];
}

// ---------------- gather-mean of x(bf16) -> A1 left half; 4 edges in flight ----------------
__global__ void k_agg1(uint* __restrict__ A1u, const int* __restrict__ rowptr,
                       const int* __restrict__ ssrc) {
    int t = blockIdx.x * 256 + threadIdx.x;
    int n = t >> 6;
    if (n >= NN) return;
    int lane = t & 63;
    int r0 = rowptr[n], r1 = rowptr[n + 1];
    float ax0 = 0.f, ay0 = 0.f, ax1 = 0.f, ay1 = 0.f;
    float ax2 = 0.f, ay2 = 0.f, ax3 = 0.f, ay3 = 0.f;
    int e = r0;
    for (; e + 4 <= r1; e += 4) {
        int s0 = ssrc[e], s1 = ssrc[e + 1], s2 = ssrc[e + 2], s3 = ssrc[e + 3];
        uint v0 = A1u[(size_t)s0 * 128 + 64 + lane];
        uint v1 = A1u[(size_t)s1 * 128 + 64 + lane];
        uint v2 = A1u[(size_t)s2 * 128 + 64 + lane];
        uint v3 = A1u[(size_t)s3 * 128 + 64 + lane];
        ax0 += bf2f(v0 & 0xffffu); ay0 += bf2f(v0 >> 16);
        ax1 += bf2f(v1 & 0xffffu); ay1 += bf2f(v1 >> 16);
        ax2 += bf2f(v2 & 0xffffu); ay2 += bf2f(v2 >> 16);
        ax3 += bf2f(v3 & 0xffffu); ay3 += bf2f(v3 >> 16);
    }
    for (; e < r1; e++) {
        int s = ssrc[e];
        uint v = A1u[(size_t)s * 128 + 64 + lane];
        ax0 += bf2f(v & 0xffffu); ay0 += bf2f(v >> 16);
    }
    float ax = (ax0 + ax1) + (ax2 + ax3);
    float ay = (ay0 + ay1) + (ay2 + ay3);
    float sc = 1.0f / fmaxf((float)(r1 - r0), 1.0f);
    A1u[(size_t)n * 128 + lane] = (uint)f2bf(ax * sc) | ((uint)f2bf(ay * sc) << 16);
}

// ---------------- layer-1 GEMM + fused layer-2 projection -----------------------------
// h1 = relu(A1@[W1l;W1r]+b1l) lives only in registers. Epilogue computes 4 per-node
// scalars: g_a=h1.pa, g_b=h1.pb (gathered later), u_a=h1.qa, u_b=h1.qb.
// Block = 4 waves x (32 rows x 256 cols); wave owns 64 cols, 2 row-tiles.
// Layouts (m89/m91-verified): A-frag A[m=lane&15][k=quad*8+j]; C/D col=lane&15, row=quad*4+reg.
__global__ __launch_bounds__(256) void k_gemm1(const ushort* __restrict__ A,
                                               const ushort* __restrict__ Bp,
                                               const float* __restrict__ bias,
                                               const float* __restrict__ pq,
                                               float2* __restrict__ g2,
                                               float2* __restrict__ u2) {
    const int K = 256, NTW = 4;
    int wave = threadIdx.x >> 6;
    int lane = threadIdx.x & 63;
    int quad = lane >> 4;
    int l15 = lane & 15;
    int mbase = blockIdx.x * 32;
    int r0 = mbase + l15;       if (r0 >= NN) r0 = NN - 1;
    int r1 = mbase + 16 + l15;  if (r1 >= NN) r1 = NN - 1;
    f32x4 acc0[NTW], acc1[NTW];
#pragma unroll
    for (int i = 0; i < NTW; i++) {
        acc0[i] = (f32x4){0.f, 0.f, 0.f, 0.f};
        acc1[i] = (f32x4){0.f, 0.f, 0.f, 0.f};
    }
    const bf16x8* bp = (const bf16x8*)Bp;
#pragma unroll
    for (int ct = 0; ct < K / 32; ct++) {
        bf16x8 a0 = *(const bf16x8*)(A + (size_t)r0 * K + ct * 32 + quad * 8);
        bf16x8 a1 = *(const bf16x8*)(A + (size_t)r1 * K + ct * 32 + quad * 8);
#pragma unroll
        for (int ntl = 0; ntl < NTW; ntl++) {
            int nt = wave * NTW + ntl;
            bf16x8 b = bp[(ct * 16 + nt) * 64 + lane];
            acc0[ntl] = __builtin_amdgcn_mfma_f32_16x16x32_bf16(a0, b, acc0[ntl], 0, 0, 0);
            acc1[ntl] = __builtin_amdgcn_mfma_f32_16x16x32_bf16(a1, b, acc1[ntl], 0, 0, 0);
        }
    }
    // epilogue: per-lane partial dots over this wave's 64 cols for 8 row-slots
    float pga[2][4] = {{0,0,0,0},{0,0,0,0}}, pgb[2][4] = {{0,0,0,0},{0,0,0,0}};
    float pua[2][4] = {{0,0,0,0},{0,0,0,0}}, pub[2][4] = {{0,0,0,0},{0,0,0,0}};
#pragma unroll
    for (int ntl = 0; ntl < NTW; ntl++) {
        int col = (wave * NTW + ntl) * 16 + l15;
        float bv = bias[col];
        float wpa = pq[col], wpb = pq[256 + col];
        float wqa = pq[512 + col], wqb = pq[768 + col];
#pragma unroll
        for (int reg = 0; reg < 4; reg++) {
            float v0 = acc0[ntl][reg] + bv;  v0 = v0 > 0.f ? v0 : 0.f;
            float v1 = acc1[ntl][reg] + bv;  v1 = v1 > 0.f ? v1 : 0.f;
            pga[0][reg] += v0 * wpa;  pgb[0][reg] += v0 * wpb;
            pua[0][reg] += v0 * wqa;  pub[0][reg] += v0 * wqb;
            pga[1][reg] += v1 * wpa;  pgb[1][reg] += v1 * wpb;
            pua[1][reg] += v1 * wqa;  pub[1][reg] += v1 * wqb;
        }
    }
    // intra-wave reduce over the 16 col-lanes
#pragma unroll
    for (int off = 1; off < 16; off <<= 1) {
#pragma unroll
        for (int rt = 0; rt < 2; rt++) {
#pragma unroll
            for (int reg = 0; reg < 4; reg++) {
                pga[rt][reg] += __shfl_xor(pga[rt][reg], off, 64);
                pgb[rt][reg] += __shfl_xor(pgb[rt][reg], off, 64);
                pua[rt][reg] += __shfl_xor(pua[rt][reg], off, 64);
                pub[rt][reg] += __shfl_xor(pub[rt][reg], off, 64);
            }
        }
    }
    // cross-wave reduce: [arr][wave][row]
    __shared__ float red[4][4][32];
    if (l15 == 0) {
#pragma unroll
        for (int rt = 0; rt < 2; rt++) {
#pragma unroll
            for (int reg = 0; reg < 4; reg++) {
                int row = rt * 16 + quad * 4 + reg;
                red[0][wave][row] = pga[rt][reg];
                red[1][wave][row] = pgb[rt][reg];
                red[2][wave][row] = pua[rt][reg];
                red[3][wave][row] = pub[rt][reg];
            }
        }
    }
    __syncthreads();
    if (threadIdx.x < 32) {
        int row = threadIdx.x;
        int m = mbase + row;
        if (m < NN) {
            float ga = (red[0][0][row] + red[0][1][row]) + (red[0][2][row] + red[0][3][row]);
            float gb = (red[1][0][row] + red[1][1][row]) + (red[1][2][row] + red[1][3][row]);
            float ua = (red[2][0][row] + red[2][1][row]) + (red[2][2][row] + red[2][3][row]);
            float ub = (red[3][0][row] + red[3][1][row]) + (red[3][2][row] + red[3][3][row]);
            g2[m] = make_float2(ga, gb);
            u2[m] = make_float2(ua, ub);
        }
    }
}

// ---------------- scalar gather-mean + final add: sa/sb per node ----------------------
__global__ void k_sagg(const float2* __restrict__ g2, const float2* __restrict__ u2,
                       const int* __restrict__ rowptr, const int* __restrict__ ssrc,
                       const float* __restrict__ cab,
                       float* __restrict__ sa, float* __restrict__ sb) {
    int n = blockIdx.x * 256 + threadIdx.x;
    if (n >= NN) return;
    int r0 = rowptr[n], r1 = rowptr[n + 1];
    float a0 = 0.f, b0 = 0.f, a1 = 0.f, b1 = 0.f;
    float a2 = 0.f, b2 = 0.f, a3 = 0.f, b3 = 0.f;
    int e = r0;
    for (; e + 4 <= r1; e += 4) {
        float2 v0 = g2[ssrc[e]];
        float2 v1 = g2[ssrc[e + 1]];
        float2 v2 = g2[ssrc[e + 2]];
        float2 v3 = g2[ssrc[e + 3]];
        a0 += v0.x; b0 += v0.y;
        a1 += v1.x; b1 += v1.y;
        a2 += v2.x; b2 += v2.y;
        a3 += v3.x; b3 += v3.y;
    }
    for (; e < r1; e++) {
        float2 v = g2[ssrc[e]];
        a0 += v.x; b0 += v.y;
    }
    float sc = 1.0f / fmaxf((float)(r1 - r0), 1.0f);
    float2 u = u2[n];
    sa[n] = ((a0 + a1) + (a2 + a3)) * sc + u.x + cab[0];
    sb[n] = ((b0 + b1) + (b2 + b3)) * sc + u.y + cab[1];
}

// ---------------- pair scorer: out[p] = sigmoid(sa[a] + sb[b] + blin) ----------------
__global__ void k_pairs(const float* __restrict__ sa, const float* __restrict__ sb,
                        const int* __restrict__ mask, const float* __restrict__ blin,
                        float* __restrict__ out) {
    int p = blockIdx.x * 256 + threadIdx.x;
    if (p >= NP) return;
    int2 m = ((const int2*)mask)[p];
    float v = sa[m.x] + sb[m.y] + blin[0];
    out[p] = 1.0f / (1.0f + __expf(-v));
}

extern "C" void kernel_launch(void* const* d_in, const int* in_sizes, int n_in,
                              void* d_out, int out_size, void* d_ws, size_t ws_size,
                              hipStream_t stream) {
    const float* x    = (const float*)d_in[0];   // [50000,128]
    const int*   ei   = (const int*)  d_in[1];   // [2,600000]
    const int*   mask = (const int*)  d_in[2];   // [200000,2]
    const float* W1l  = (const float*)d_in[3];   // [128,256]
    const float* b1l  = (const float*)d_in[4];   // [256]
    const float* W1r  = (const float*)d_in[5];   // [128,256]
    const float* W2l  = (const float*)d_in[6];   // [256,128]
    const float* b2l  = (const float*)d_in[7];   // [128]
    const float* W2r  = (const float*)d_in[8];   // [256,128]
    const float* Wlin = (const float*)d_in[9];   // [256,1]
    const float* blin = (const float*)d_in[10];  // [1]
    float* out = (float*)d_out;                  // [200000,1]

    const int* src = ei;
    const int* dst = ei + NE;

    char* ws = (char*)d_ws;
    int*    deg    = (int*)(ws);                             // 200 KB
    int*    rowptr = (int*)(ws + (size_t)1 * (1 << 20));
    int*    cursor = (int*)(ws + (size_t)2 * (1 << 20));
    int*    ssrc   = (int*)(ws + (size_t)3 * (1 << 20));     // 2.4 MB
    int*    excl   = (int*)(ws + (size_t)6 * (1 << 20));     // 200 KB
    int*    bsum   = (int*)(ws + (size_t)7 * (1 << 20));     // 196 B
    ushort* Bp1    = (ushort*)(ws + (size_t)8 * (1 << 20));  // 128 KB
    float*  pq     = (float*)(ws + (size_t)9 * (1 << 20));   // 4 KB
    float*  cab    = (float*)(ws + (size_t)9 * (1 << 20) + 65536);
    float*  sa     = (float*)(ws + (size_t)10 * (1 << 20));  // 200 KB
    float*  sb     = (float*)(ws + (size_t)11 * (1 << 20));  // 200 KB
    float2* g2     = (float2*)(ws + (size_t)12 * (1 << 20)); // 400 KB
    float2* u2     = (float2*)(ws + (size_t)13 * (1 << 20)); // 400 KB
    uint*   A1u    = (uint*)(ws + (size_t)14 * (1 << 20));   // [50000,256] bf16 = 25.6 MB

    hipMemsetAsync(deg, 0, (size_t)NN * 4, stream);

    k_pre  <<<(T_CAB + 255) / 256, 256, 0, stream>>>(x, A1u, dst, deg,
                                                     W1l, W1r, Bp1,
                                                     W2l, W2r, Wlin, b2l, pq, cab);
    k_scan1<<<NB_SCAN, 1024, 0, stream>>>(deg, excl, bsum);
    k_scan2<<<1, 64, 0, stream>>>(bsum);
    k_scan3<<<NB_SCAN, 1024, 0, stream>>>(excl, bsum, rowptr, cursor);
    k_fill <<<(NE + 255) / 256, 256, 0, stream>>>(src, dst, cursor, ssrc);

    k_agg1 <<<NN / 4, 256, 0, stream>>>(A1u, rowptr, ssrc);
    k_gemm1<<<(NN + 31) / 32, 256, 0, stream>>>((const ushort*)A1u, Bp1, b1l,
                                                pq, g2, u2);
    k_sagg <<<(NN + 255) / 256, 256, 0, stream>>>(g2, u2, rowptr, ssrc, cab, sa, sb);
    k_pairs<<<(NP + 255) / 256, 256, 0, stream>>>(sa, sb, mask, blin, out);
}